// Round 11
// baseline (534.794 us; speedup 1.0000x reference)
//
#include <hip/hip_runtime.h>
#include <stdint.h>
#include <stddef.h>

// ---------------------------------------------------------------- types
typedef __attribute__((ext_vector_type(8))) short short8;
typedef __attribute__((ext_vector_type(4))) short short4v;
typedef __attribute__((ext_vector_type(4))) float floatx4;

#define DEV __device__ __forceinline__

DEV float bf2f(short s) {
    union { float f; uint32_t u; } v;
    v.u = ((uint32_t)(uint16_t)s) << 16;
    return v.f;
}
DEV short f2bf(float f) {
    union { float f; uint32_t u; } v;
    v.f = f;
    uint32_t u = v.u + 0x7FFFu + ((v.u >> 16) & 1u);  // RNE
    return (short)(u >> 16);
}
DEV short f2bf_tr(float f) {           // truncate (1 op) — P matrix only
    union { float f; uint32_t u; } v;
    v.f = f;
    return (short)(v.u >> 16);
}

// ---------------------------------------------------------------- GEMM core
// C(M,N) = A(M,K) @ Bt(N,K)^T ; 256x128 tile, 4 waves each owning 128x64
// (42.7 FLOP per LDS byte vs 32 at 64x64 -> no longer LDS-read-bound).
// BK=32, dbuf staging via global_load_lds. M%256==0, N%128==0.
template<int BIAS, int RELU, int OUTBF>
__global__ __launch_bounds__(256) void gemm_bt(
    const short* __restrict__ A, const short* __restrict__ Bt,
    const float* __restrict__ bias, void* __restrict__ Cout,
    int M, int N, int K)
{
    __shared__ short Alds[2][256 * 32];   // 32KB
    __shared__ short Blds[2][128 * 32];   // 16KB
    const int tid  = threadIdx.x;
    const int wave = tid >> 6, lane = tid & 63;
    const int g = lane >> 4, li = lane & 15;

    const int gx = gridDim.x;
    int flat = blockIdx.y * gx + blockIdx.x;
    const int nwg = gx * gridDim.y;
    flat = (flat & 7) * (nwg >> 3) + (flat >> 3);   // XCD swizzle (nwg%8==0)
    const long bm = (long)(flat % gx) * 256;
    const long bn = (long)(flat / gx) * 128;

    const int wrow = (wave >> 1) * 128;
    const int wcol = (wave & 1) * 64;
    const int srowA = wave * 64 + (lane >> 2);
    const int srowB = wave * 32 + (lane >> 2);
    const int scol = (lane & 3) * 8;
    const short* Ap = A + (bm + srowA) * (long)K + scol;
    const short* Bp = Bt + (bn + srowB) * (long)K + scol;

    auto STAGE = [&](int buf, int k0) {
#pragma unroll
        for (int r = 0; r < 64; r += 16)
            __builtin_amdgcn_global_load_lds(
                (const __attribute__((address_space(1))) void*)(Ap + (long)r * K + k0),
                (__attribute__((address_space(3))) void*)(&Alds[buf][wave * 2048 + r * 32]),
                16, 0, 0);
#pragma unroll
        for (int r = 0; r < 32; r += 16)
            __builtin_amdgcn_global_load_lds(
                (const __attribute__((address_space(1))) void*)(Bp + (long)r * K + k0),
                (__attribute__((address_space(3))) void*)(&Blds[buf][wave * 1024 + r * 32]),
                16, 0, 0);
    };

    floatx4 acc[8][4];
#pragma unroll
    for (int i = 0; i < 8; i++)
#pragma unroll
        for (int j = 0; j < 4; j++) acc[i][j] = (floatx4){0.f, 0.f, 0.f, 0.f};

    STAGE(0, 0);
    __syncthreads();
    int cur = 0;
    for (int k0 = 0; k0 < K; k0 += 32) {
        if (k0 + 32 < K) STAGE(cur ^ 1, k0 + 32);

        short8 bfr[4];
#pragma unroll
        for (int ni = 0; ni < 4; ni++)
            bfr[ni] = *(const short8*)(&Blds[cur][(wcol + ni * 16 + li) * 32 + g * 8]);
#pragma unroll
        for (int mi = 0; mi < 8; mi++) {
            short8 af = *(const short8*)(&Alds[cur][(wrow + mi * 16 + li) * 32 + g * 8]);
#pragma unroll
            for (int ni = 0; ni < 4; ni++)
                acc[mi][ni] = __builtin_amdgcn_mfma_f32_16x16x32_bf16(
                    af, bfr[ni], acc[mi][ni], 0, 0, 0);
        }

        __syncthreads();
        cur ^= 1;
    }

    float* Cf = (float*)Cout;
    short* Cb = (short*)Cout;
#pragma unroll
    for (int mi = 0; mi < 8; mi++) {
#pragma unroll
        for (int ni = 0; ni < 4; ni++) {
            const long col = bn + wcol + ni * 16 + li;
            const float bv = BIAS ? bias[col] : 0.f;
#pragma unroll
            for (int i = 0; i < 4; i++) {
                const long row = bm + wrow + mi * 16 + g * 4 + i;
                float v = acc[mi][ni][i] + bv;
                if (RELU) v = fmaxf(v, 0.f);
                if (OUTBF) Cb[row * N + col] = f2bf(v);
                else       Cf[row * N + col] = v;
            }
        }
    }
}

// Dual-A + V^T-epilogue variant (256x128 tile).
// A = A0 for cols < nsplit, A1 otherwise. Cols < vtoff -> C (bf16, ld ldc);
// cols >= vtoff -> V^T into VT[b][d][key] (key = row & mask, b = row>>nkvlog).
__global__ __launch_bounds__(256) void gemm_bt2vt(
    const short* __restrict__ A0, const short* __restrict__ A1,
    const short* __restrict__ Bt, short* __restrict__ Cout,
    short* __restrict__ VT,
    int M, int N, int K, int nsplit, int ldc, int vtoff, int nkvlog)
{
    __shared__ short Alds[2][256 * 32];
    __shared__ short Blds[2][128 * 32];
    const int tid  = threadIdx.x;
    const int wave = tid >> 6, lane = tid & 63;
    const int g = lane >> 4, li = lane & 15;

    const int gx = gridDim.x;
    int flat = blockIdx.y * gx + blockIdx.x;
    const int nwg = gx * gridDim.y;
    flat = (flat & 7) * (nwg >> 3) + (flat >> 3);
    const long bm = (long)(flat % gx) * 256;
    const long bn = (long)(flat / gx) * 128;

    const int wrow = (wave >> 1) * 128;
    const int wcol = (wave & 1) * 64;
    const int srowA = wave * 64 + (lane >> 2);
    const int srowB = wave * 32 + (lane >> 2);
    const int scol = (lane & 3) * 8;
    const short* A = (bn < nsplit) ? A0 : A1;
    const short* Ap = A + (bm + srowA) * (long)K + scol;
    const short* Bp = Bt + (bn + srowB) * (long)K + scol;

    auto STAGE = [&](int buf, int k0) {
#pragma unroll
        for (int r = 0; r < 64; r += 16)
            __builtin_amdgcn_global_load_lds(
                (const __attribute__((address_space(1))) void*)(Ap + (long)r * K + k0),
                (__attribute__((address_space(3))) void*)(&Alds[buf][wave * 2048 + r * 32]),
                16, 0, 0);
#pragma unroll
        for (int r = 0; r < 32; r += 16)
            __builtin_amdgcn_global_load_lds(
                (const __attribute__((address_space(1))) void*)(Bp + (long)r * K + k0),
                (__attribute__((address_space(3))) void*)(&Blds[buf][wave * 1024 + r * 32]),
                16, 0, 0);
    };

    floatx4 acc[8][4];
#pragma unroll
    for (int i = 0; i < 8; i++)
#pragma unroll
        for (int j = 0; j < 4; j++) acc[i][j] = (floatx4){0.f, 0.f, 0.f, 0.f};

    STAGE(0, 0);
    __syncthreads();
    int cur = 0;
    for (int k0 = 0; k0 < K; k0 += 32) {
        if (k0 + 32 < K) STAGE(cur ^ 1, k0 + 32);
        short8 bfr[4];
#pragma unroll
        for (int ni = 0; ni < 4; ni++)
            bfr[ni] = *(const short8*)(&Blds[cur][(wcol + ni * 16 + li) * 32 + g * 8]);
#pragma unroll
        for (int mi = 0; mi < 8; mi++) {
            short8 af = *(const short8*)(&Alds[cur][(wrow + mi * 16 + li) * 32 + g * 8]);
#pragma unroll
            for (int ni = 0; ni < 4; ni++)
                acc[mi][ni] = __builtin_amdgcn_mfma_f32_16x16x32_bf16(
                    af, bfr[ni], acc[mi][ni], 0, 0, 0);
        }
        __syncthreads();
        cur ^= 1;
    }

    if (bn < vtoff) {
#pragma unroll
        for (int mi = 0; mi < 8; mi++)
#pragma unroll
            for (int ni = 0; ni < 4; ni++) {
                const long col = bn + wcol + ni * 16 + li;
#pragma unroll
                for (int i = 0; i < 4; i++) {
                    const long row = bm + wrow + mi * 16 + g * 4 + i;
                    Cout[row * ldc + col] = f2bf(acc[mi][ni][i]);
                }
            }
    } else {
        const int mask = (1 << nkvlog) - 1;
#pragma unroll
        for (int mi = 0; mi < 8; mi++) {
            const int row0 = (int)(bm + wrow + mi * 16 + g * 4);
            const int bb = row0 >> nkvlog;
            const int key0 = row0 & mask;
#pragma unroll
            for (int ni = 0; ni < 4; ni++) {
                const int d = (int)(bn + wcol + ni * 16 + li) - vtoff;
                short4v o = { f2bf(acc[mi][ni][0]), f2bf(acc[mi][ni][1]),
                              f2bf(acc[mi][ni][2]), f2bf(acc[mi][ni][3]) };
                *(short4v*)(VT + ((long)(bb * 512 + d) << nkvlog) + key0) = o;
            }
        }
    }
}

// Split-K=2 variant (256x128 tile): blockIdx.z picks K-half; f32 partials,
// bias applied in partial 0 only; partials summed in ln_res.
template<int BIAS>
__global__ __launch_bounds__(256) void gemm_bt_sk(
    const short* __restrict__ A, const short* __restrict__ Bt,
    const float* __restrict__ bias, float* __restrict__ Cout,
    int M, int N, int K)
{
    __shared__ short Alds[2][256 * 32];
    __shared__ short Blds[2][128 * 32];
    const int tid  = threadIdx.x;
    const int wave = tid >> 6, lane = tid & 63;
    const int g = lane >> 4, li = lane & 15;
    const int z = blockIdx.z;
    const int Kh = K >> 1;

    const int gx = gridDim.x;
    int flat = blockIdx.y * gx + blockIdx.x;
    const int nwg = gx * gridDim.y;
    flat = (flat & 7) * (nwg >> 3) + (flat >> 3);
    const long bm = (long)(flat % gx) * 256;
    const long bn = (long)(flat / gx) * 128;

    const int wrow = (wave >> 1) * 128;
    const int wcol = (wave & 1) * 64;
    const int srowA = wave * 64 + (lane >> 2);
    const int srowB = wave * 32 + (lane >> 2);
    const int scol = (lane & 3) * 8;
    const short* Ap = A + (bm + srowA) * (long)K + scol + (long)z * Kh;
    const short* Bp = Bt + (bn + srowB) * (long)K + scol + (long)z * Kh;
    float* C = Cout + (long)z * M * N;

    auto STAGE = [&](int buf, int k0) {
#pragma unroll
        for (int r = 0; r < 64; r += 16)
            __builtin_amdgcn_global_load_lds(
                (const __attribute__((address_space(1))) void*)(Ap + (long)r * K + k0),
                (__attribute__((address_space(3))) void*)(&Alds[buf][wave * 2048 + r * 32]),
                16, 0, 0);
#pragma unroll
        for (int r = 0; r < 32; r += 16)
            __builtin_amdgcn_global_load_lds(
                (const __attribute__((address_space(1))) void*)(Bp + (long)r * K + k0),
                (__attribute__((address_space(3))) void*)(&Blds[buf][wave * 1024 + r * 32]),
                16, 0, 0);
    };

    floatx4 acc[8][4];
#pragma unroll
    for (int i = 0; i < 8; i++)
#pragma unroll
        for (int j = 0; j < 4; j++) acc[i][j] = (floatx4){0.f, 0.f, 0.f, 0.f};

    STAGE(0, 0);
    __syncthreads();
    int cur = 0;
    for (int k0 = 0; k0 < Kh; k0 += 32) {
        if (k0 + 32 < Kh) STAGE(cur ^ 1, k0 + 32);
        short8 bfr[4];
#pragma unroll
        for (int ni = 0; ni < 4; ni++)
            bfr[ni] = *(const short8*)(&Blds[cur][(wcol + ni * 16 + li) * 32 + g * 8]);
#pragma unroll
        for (int mi = 0; mi < 8; mi++) {
            short8 af = *(const short8*)(&Alds[cur][(wrow + mi * 16 + li) * 32 + g * 8]);
#pragma unroll
            for (int ni = 0; ni < 4; ni++)
                acc[mi][ni] = __builtin_amdgcn_mfma_f32_16x16x32_bf16(
                    af, bfr[ni], acc[mi][ni], 0, 0, 0);
        }
        __syncthreads();
        cur ^= 1;
    }

#pragma unroll
    for (int mi = 0; mi < 8; mi++)
#pragma unroll
        for (int ni = 0; ni < 4; ni++) {
            const long col = bn + wcol + ni * 16 + li;
            const float bv = (BIAS && z == 0) ? bias[col] : 0.f;
#pragma unroll
            for (int i = 0; i < 4; i++) {
                const long row = bm + wrow + mi * 16 + g * 4 + i;
                C[row * N + col] = acc[mi][ni][i] + bv;
            }
        }
}

// ---------------------------------------------------------------- attention
// EXACT R9 kernel (KT=32, 32 q/wave, T14 async staging, static-max softmax,
// LD=68/LDP=36, XCD-locality decode). KT=64 regressed twice -> frozen.
__global__ __launch_bounds__(256) void attn_kernel(
    const short* __restrict__ Qg, const short* __restrict__ Kg,
    const short* __restrict__ VTg, short* __restrict__ Og,
    int NQ, int NK, int ldq, int ldk)
{
    constexpr int LD = 68, LDP = 36;
    __shared__ short Klds[32 * LD];       // [key][d]
    __shared__ short Vlds[64 * LD];       // [d][key]
    __shared__ short Plds[4][32 * LDP];   // per-wave [q][key], 32 q rows

    const int tid = threadIdx.x;
    const int wave = tid >> 6, lane = tid & 63;
    const int g = lane >> 4, li = lane & 15;

    const int nqb = NQ >> 7;
    const int i   = blockIdx.x;
    const int xcd = i & 7;
    const int t   = i >> 3;
    const int c   = t % nqb;
    const int gh  = t / nqb;
    const int grp = xcd + 8 * gh;         // 0..63
    const int b   = grp >> 3, h = grp & 7;
    const int q0  = c * 128 + wave * 32;

    const short* qptrA = Qg + ((long)(b * NQ + q0 + li) * ldq + h * 64);
    const short* qptrB = qptrA + (long)16 * ldq;
    short8 qfA[2], qfB[2];
#pragma unroll
    for (int f = 0; f < 2; f++) {
        short8 ta = *(const short8*)(qptrA + f * 32 + g * 8);
        short8 tb = *(const short8*)(qptrB + f * 32 + g * 8);
#pragma unroll
        for (int ii = 0; ii < 8; ii++) {
            ta[ii] = f2bf(bf2f(ta[ii]) * 0.18033688011112042f);
            tb[ii] = f2bf(bf2f(tb[ii]) * 0.18033688011112042f);
        }
        qfA[f] = ta; qfB[f] = tb;
    }

    floatx4 accA[4], accB[4];
#pragma unroll
    for (int s = 0; s < 4; s++) {
        accA[s] = (floatx4){0.f, 0.f, 0.f, 0.f};
        accB[s] = (floatx4){0.f, 0.f, 0.f, 0.f};
    }
    float lsumA = 0.f, lsumB = 0.f;

    const int skey = tid >> 3, sdc = (tid & 7) * 8;  // K staging: 32 keys x 64 d
    const int svd = tid >> 2, svk = (tid & 3) * 8;   // VT staging: 64 d x 32 keys
    const short* kp = Kg + (long)b * NK * ldk + h * 64 + (long)skey * ldk + sdc;
    const short* vp = VTg + ((long)(b * 512 + h * 64 + svd)) * NK + svk;

    short8 kreg = *(const short8*)kp;  kp += (long)32 * ldk;
    short8 vreg = *(const short8*)vp;  vp += 32;

    for (int kt = 0; kt < NK; kt += 32) {
        __syncthreads();
        *(short8*)(Klds + skey * LD + sdc) = kreg;
        *(short8*)(Vlds + svd * LD + svk) = vreg;
        __syncthreads();
        if (kt + 32 < NK) {
            kreg = *(const short8*)kp;  kp += (long)32 * ldk;
            vreg = *(const short8*)vp;  vp += 32;
        }

        // S^T subtiles: lane holds S[key = sub*16 + 4g + i][q = li (A) / 16+li (B)]
        floatx4 sA0 = (floatx4){0.f, 0.f, 0.f, 0.f};
        floatx4 sA1 = (floatx4){0.f, 0.f, 0.f, 0.f};
        floatx4 sB0 = (floatx4){0.f, 0.f, 0.f, 0.f};
        floatx4 sB1 = (floatx4){0.f, 0.f, 0.f, 0.f};
        {
            short8 k00 = *(const short8*)(Klds + li * LD + g * 8);
            short8 k01 = *(const short8*)(Klds + li * LD + 32 + g * 8);
            short8 k10 = *(const short8*)(Klds + (16 + li) * LD + g * 8);
            short8 k11 = *(const short8*)(Klds + (16 + li) * LD + 32 + g * 8);
            sA0 = __builtin_amdgcn_mfma_f32_16x16x32_bf16(k00, qfA[0], sA0, 0, 0, 0);
            sA0 = __builtin_amdgcn_mfma_f32_16x16x32_bf16(k01, qfA[1], sA0, 0, 0, 0);
            sA1 = __builtin_amdgcn_mfma_f32_16x16x32_bf16(k10, qfA[0], sA1, 0, 0, 0);
            sA1 = __builtin_amdgcn_mfma_f32_16x16x32_bf16(k11, qfA[1], sA1, 0, 0, 0);
            sB0 = __builtin_amdgcn_mfma_f32_16x16x32_bf16(k00, qfB[0], sB0, 0, 0, 0);
            sB0 = __builtin_amdgcn_mfma_f32_16x16x32_bf16(k01, qfB[1], sB0, 0, 0, 0);
            sB1 = __builtin_amdgcn_mfma_f32_16x16x32_bf16(k10, qfB[0], sB1, 0, 0, 0);
            sB1 = __builtin_amdgcn_mfma_f32_16x16x32_bf16(k11, qfB[1], sB1, 0, 0, 0);
        }

        // static-max softmax: p = exp2(S)
        const float a0 = exp2f(sA0[0]), a1 = exp2f(sA0[1]);
        const float a2 = exp2f(sA0[2]), a3 = exp2f(sA0[3]);
        const float a4 = exp2f(sA1[0]), a5 = exp2f(sA1[1]);
        const float a6 = exp2f(sA1[2]), a7 = exp2f(sA1[3]);
        lsumA += ((a0 + a1) + (a2 + a3)) + ((a4 + a5) + (a6 + a7));
        const float b0 = exp2f(sB0[0]), b1 = exp2f(sB0[1]);
        const float b2 = exp2f(sB0[2]), b3 = exp2f(sB0[3]);
        const float b4 = exp2f(sB1[0]), b5 = exp2f(sB1[1]);
        const float b6 = exp2f(sB1[2]), b7 = exp2f(sB1[3]);
        lsumB += ((b0 + b1) + (b2 + b3)) + ((b4 + b5) + (b6 + b7));

        short4v pa0 = { f2bf_tr(a0), f2bf_tr(a1), f2bf_tr(a2), f2bf_tr(a3) };
        short4v pa1 = { f2bf_tr(a4), f2bf_tr(a5), f2bf_tr(a6), f2bf_tr(a7) };
        short4v pb0 = { f2bf_tr(b0), f2bf_tr(b1), f2bf_tr(b2), f2bf_tr(b3) };
        short4v pb1 = { f2bf_tr(b4), f2bf_tr(b5), f2bf_tr(b6), f2bf_tr(b7) };
        *(short4v*)(Plds[wave] + li * LDP + g * 4) = pa0;
        *(short4v*)(Plds[wave] + li * LDP + 16 + g * 4) = pa1;
        *(short4v*)(Plds[wave] + (16 + li) * LDP + g * 4) = pb0;
        *(short4v*)(Plds[wave] + (16 + li) * LDP + 16 + g * 4) = pb1;
        short8 pfA = *(const short8*)(Plds[wave] + li * LDP + g * 8);
        short8 pfB = *(const short8*)(Plds[wave] + (16 + li) * LDP + g * 8);

        // O^T slices: acc[s] += VT_slice(16d x 32k) . P^T(32k x 16q)
#pragma unroll
        for (int s = 0; s < 4; s++) {
            short8 vf = *(const short8*)(Vlds + (s * 16 + li) * LD + g * 8);
            accA[s] = __builtin_amdgcn_mfma_f32_16x16x32_bf16(vf, pfA, accA[s], 0, 0, 0);
            accB[s] = __builtin_amdgcn_mfma_f32_16x16x32_bf16(vf, pfB, accB[s], 0, 0, 0);
        }
    }

    lsumA += __shfl_xor(lsumA, 16);
    lsumA += __shfl_xor(lsumA, 32);
    lsumB += __shfl_xor(lsumB, 16);
    lsumB += __shfl_xor(lsumB, 32);
    const float invA = 1.f / lsumA;
    const float invB = 1.f / lsumB;
    short* optrA = Og + ((long)(b * NQ + q0 + li) * 512 + h * 64);
    short* optrB = optrA + (long)16 * 512;
#pragma unroll
    for (int s = 0; s < 4; s++) {
        short4v oa = { f2bf(accA[s][0] * invA), f2bf(accA[s][1] * invA),
                       f2bf(accA[s][2] * invA), f2bf(accA[s][3] * invA) };
        short4v ob = { f2bf(accB[s][0] * invB), f2bf(accB[s][1] * invB),
                       f2bf(accB[s][2] * invB), f2bf(accB[s][3] * invB) };
        *(short4v*)(optrA + s * 16 + g * 4) = oa;
        *(short4v*)(optrB + s * 16 + g * 4) = ob;
    }
}

// ---------------------------------------------------------------- small kernels
__global__ __launch_bounds__(256) void add_conv2(
    const float* __restrict__ a, const float* __restrict__ b,
    float* __restrict__ of, short* __restrict__ ob1, short* __restrict__ ob2)
{
    const long i = (long)(blockIdx.x * 256 + threadIdx.x) * 4;
    const float4 va = *(const float4*)(a + i);
    float4 vs = va;
    if (b) {
        const float4 vb = *(const float4*)(b + i);
        vs.x += vb.x; vs.y += vb.y; vs.z += vb.z; vs.w += vb.w;
    }
    if (of) *(float4*)(of + i) = vs;
    short4v o1 = { f2bf(vs.x), f2bf(vs.y), f2bf(vs.z), f2bf(vs.w) };
    *(short4v*)(ob1 + i) = o1;
    if (ob2) {
        short4v o2 = { f2bf(va.x), f2bf(va.y), f2bf(va.z), f2bf(va.w) };
        *(short4v*)(ob2 + i) = o2;
    }
}

// y = LayerNorm(X [+X2])*g + b + res [+ postadd]; outF f32, outB bf16 (opt)
__global__ __launch_bounds__(256) void ln_res_kernel(
    const float* __restrict__ X, const float* __restrict__ X2,
    const float* __restrict__ gam, const float* __restrict__ bet,
    const float* __restrict__ res, const float* __restrict__ postadd,
    float* __restrict__ outF, short* __restrict__ outB)
{
    const int row = blockIdx.x * 4 + (threadIdx.x >> 6);
    const int lane = threadIdx.x & 63;
    const long base = (long)row * 512 + lane * 8;
    float x[8];
    *(float4*)(x) = *(const float4*)(X + base);
    *(float4*)(x + 4) = *(const float4*)(X + base + 4);
    if (X2) {
        float x2[8];
        *(float4*)(x2) = *(const float4*)(X2 + base);
        *(float4*)(x2 + 4) = *(const float4*)(X2 + base + 4);
#pragma unroll
        for (int i = 0; i < 8; i++) x[i] += x2[i];
    }
    float s = x[0] + x[1] + x[2] + x[3] + x[4] + x[5] + x[6] + x[7];
#pragma unroll
    for (int o = 1; o < 64; o <<= 1) s += __shfl_xor(s, o);
    const float mu = s * (1.0f / 512.0f);
    float vs = 0.f;
#pragma unroll
    for (int i = 0; i < 8; i++) { const float d = x[i] - mu; vs += d * d; }
#pragma unroll
    for (int o = 1; o < 64; o <<= 1) vs += __shfl_xor(vs, o);
    const float rs = rsqrtf(vs * (1.0f / 512.0f) + 1e-5f);

    float gv[8], bv[8], rv[8];
    *(float4*)(gv) = *(const float4*)(gam + lane * 8);
    *(float4*)(gv + 4) = *(const float4*)(gam + lane * 8 + 4);
    *(float4*)(bv) = *(const float4*)(bet + lane * 8);
    *(float4*)(bv + 4) = *(const float4*)(bet + lane * 8 + 4);
    *(float4*)(rv) = *(const float4*)(res + base);
    *(float4*)(rv + 4) = *(const float4*)(res + base + 4);

    float y[8];
#pragma unroll
    for (int i = 0; i < 8; i++) y[i] = (x[i] - mu) * rs * gv[i] + bv[i] + rv[i];
    if (postadd) {
        float pv[8];
        *(float4*)(pv) = *(const float4*)(postadd + base);
        *(float4*)(pv + 4) = *(const float4*)(postadd + base + 4);
#pragma unroll
        for (int i = 0; i < 8; i++) y[i] += pv[i];
    }
    *(float4*)(outF + base) = *(float4*)(y);
    *(float4*)(outF + base + 4) = *(float4*)(y + 4);
    if (outB) {
        short8 ob;
#pragma unroll
        for (int i = 0; i < 8; i++) ob[i] = f2bf(y[i]);
        *(short8*)(outB + base) = ob;
    }
}

// batched W (K,N) f32 -> Wt (N,K) bf16; blockIdx.z selects source/dest
__global__ __launch_bounds__(256) void wtrans8(
    const float* __restrict__ w0, const float* __restrict__ w1,
    const float* __restrict__ w2, const float* __restrict__ w3,
    const float* __restrict__ w4, const float* __restrict__ w5,
    const float* __restrict__ w6, const float* __restrict__ w7,
    short* __restrict__ o0, short* __restrict__ o1,
    short* __restrict__ o2, short* __restrict__ o3,
    short* __restrict__ o4, short* __restrict__ o5,
    short* __restrict__ o6, short* __restrict__ o7,
    int K, int N)
{
    const float* Ws[8] = {w0, w1, w2, w3, w4, w5, w6, w7};
    short* Os[8] = {o0, o1, o2, o3, o4, o5, o6, o7};
    const float* W = Ws[blockIdx.z];
    short* Wt = Os[blockIdx.z];
    __shared__ short t[32][33];
    const int n0 = blockIdx.x * 32, k0 = blockIdx.y * 32;
    const int tx = threadIdx.x & 31, ty = threadIdx.x >> 5;
    for (int r = ty; r < 32; r += 8)
        t[r][tx] = f2bf(W[(long)(k0 + r) * N + n0 + tx]);
    __syncthreads();
    for (int r = ty; r < 32; r += 8)
        Wt[(long)(n0 + r) * K + k0 + tx] = t[tx][r];
}

// ---------------------------------------------------------------- launch
extern "C" void kernel_launch(void* const* d_in, const int* in_sizes, int n_in,
                              void* d_out, int out_size, void* d_ws, size_t ws_size,
                              hipStream_t stream)
{
    (void)in_sizes; (void)n_in; (void)out_size; (void)ws_size;
    const float* tgt   = (const float*)d_in[0];
    const float* mem   = (const float*)d_in[1];
    const float* pos   = (const float*)d_in[2];
    const float* qpos  = (const float*)d_in[3];
    const float* a0_wq = (const float*)d_in[4];
    const float* a0_wk = (const float*)d_in[5];
    const float* a0_wv = (const float*)d_in[6];
    const float* a0_wo = (const float*)d_in[7];
    const float* a0_bo = (const float*)d_in[8];
    const float* a0_g  = (const float*)d_in[9];
    const float* a0_b  = (const float*)d_in[10];
    const float* f0_w1 = (const float*)d_in[11];
    const float* f0_b1 = (const float*)d_in[12];
    const float* f0_w2 = (const float*)d_in[13];
    const float* f0_b2 = (const float*)d_in[14];
    const float* f0_g  = (const float*)d_in[15];
    const float* f0_b  = (const float*)d_in[16];
    const float* a1_wq = (const float*)d_in[17];
    const float* a1_wk = (const float*)d_in[18];
    const float* a1_wv = (const float*)d_in[19];
    const float* a1_wo = (const float*)d_in[20];
    const float* a1_bo = (const float*)d_in[21];
    const float* a1_g  = (const float*)d_in[22];
    const float* a1_b  = (const float*)d_in[23];
    const float* f1_w1 = (const float*)d_in[24];
    const float* f1_b1 = (const float*)d_in[25];
    const float* f1_w2 = (const float*)d_in[26];
    const float* f1_b2 = (const float*)d_in[27];
    const float* f1_g  = (const float*)d_in[28];
    const float* f1_b  = (const float*)d_in[29];

    const int M1 = 8 * 1024;   // 8192 query rows
    const int M2 = 8 * 2048;   // 16384 memory rows
    const size_t MB = 1ull << 20;
    char* ws = (char*)d_ws;

    float* resid = (float*)(ws + 0 * MB);       // 16MB
    float* xf    = (float*)(ws + 16 * MB);      // 16MB
    short* xb    = (short*)(ws + 32 * MB);      // 8MB
    short* wb    = (short*)(ws + 40 * MB);      // 12MB bf16 W^T bank
    short* a0_wqt = wb;            short* a0_wkt = wb + 262144;   // Wq^T||Wk^T||Wv^T
    short* a0_wvt = wb + 524288;   short* a0_wot = wb + 786432;
    short* f0_w1t = wb + 1048576;  short* f0_w2t = wb + 2097152;
    short* a1_wqt = wb + 3145728;  short* a1_wkt = wb + 3407872;   // Wk^T||Wv^T
    short* a1_wvt = wb + 3670016;  short* a1_wot = wb + 3932160;
    short* f1_w1t = wb + 4194304;  short* f1_w2t = wb + 5242880;
    char* S = ws + 56 * MB;                      // stage scratch (max used: +88MB)

    wtrans8<<<dim3(16, 16, 8), 256, 0, stream>>>(
        a0_wq, a0_wk, a0_wv, a0_wo, a1_wq, a1_wk, a1_wv, a1_wo,
        a0_wqt, a0_wkt, a0_wvt, a0_wot, a1_wqt, a1_wkt, a1_wvt, a1_wot, 512, 512);
    wtrans8<<<dim3(64, 16, 2), 256, 0, stream>>>(
        f0_w1, f1_w1, nullptr, nullptr, nullptr, nullptr, nullptr, nullptr,
        f0_w1t, f1_w1t, nullptr, nullptr, nullptr, nullptr, nullptr, nullptr, 512, 2048);
    wtrans8<<<dim3(16, 64, 2), 256, 0, stream>>>(
        f0_w2, f1_w2, nullptr, nullptr, nullptr, nullptr, nullptr, nullptr,
        f0_w2t, f1_w2t, nullptr, nullptr, nullptr, nullptr, nullptr, nullptr, 2048, 512);

    // ---------------- block A0: self-attention ----------------
    short* QKs  = (short*)(S + 0 * MB);    // 16MB: [8192][1024] = Q||K (ld 1024)
    short* VsT  = (short*)(S + 16 * MB);   // 8MB:  [8][512][1024] V^T
    short* AOs  = (short*)(S + 24 * MB);   // 8MB
    float* P0a  = (float*)(S + 32 * MB);   // 16MB
    float* P1a  = (float*)(S + 48 * MB);   // 16MB
    short* q0b  = (short*)(S + 64 * MB);   // 8MB
    short* tgtb = (short*)(S + 72 * MB);   // 8MB

    add_conv2<<<4096, 256, 0, stream>>>(tgt, qpos, resid, q0b, tgtb);

    // fused QKV projection; V section written directly transposed to VsT
    gemm_bt2vt<<<dim3(32, 12), 256, 0, stream>>>(q0b, tgtb, a0_wqt, QKs, VsT,
                                                 M1, 1536, 512, 1024, 1024, 1024, 10);
    attn_kernel<<<512, 256, 0, stream>>>(QKs, QKs + 512, VsT, AOs,
                                         1024, 1024, 1024, 1024);
    gemm_bt_sk<1><<<dim3(32, 4, 2), 256, 0, stream>>>(AOs, a0_wot, a0_bo, P0a,
                                                      M1, 512, 512);
    ln_res_kernel<<<2048, 256, 0, stream>>>(P0a, P1a, a0_g, a0_b, resid, nullptr, xf, xb);

    // ---------------- block F0: FFN ----------------
    short* Hb  = (short*)(S + 0 * MB);     // 32MB (QKs/VsT/AOs dead)
    float* P0f = (float*)(S + 32 * MB);    // 16MB (over dead P0a)
    float* P1f = (float*)(S + 48 * MB);    // 16MB (over dead P1a)
    short* qcb = (short*)(S + 80 * MB);    // 8MB (A1 q input, written by ln)
    gemm_bt<1,1,1><<<dim3(32, 16), 256, 0, stream>>>(xb, f0_w1t, f0_b1, Hb, M1, 2048, 512);
    gemm_bt_sk<1><<<dim3(32, 4, 2), 256, 0, stream>>>(Hb, f0_w2t, f0_b2, P0f,
                                                      M1, 512, 2048);
    // y = LN(P0+P1)+xf ; resid = y+qpos (f32), qcb = bf16(y+qpos)
    ln_res_kernel<<<2048, 256, 0, stream>>>(P0f, P1f, f0_g, f0_b, xf, qpos, resid, qcb);

    // ---------------- block A1: cross-attention ----------------
    // Lifetimes: Hb dead after FFN2-sk; P0f/P1f dead after F0-ln; q0b/tgtb dead.
    // Kc/VcT dead after attn -> P0c/P1c overwrite them.
    short* kcb  = (short*)(S + 0 * MB);    // 16MB (over dead Hb)
    short* memb = (short*)(S + 16 * MB);   // 16MB
    short* Kc   = (short*)(S + 32 * MB);   // 16MB: [16384][512] dense K
    short* VcT  = (short*)(S + 48 * MB);   // 16MB: [8][512][2048] V^T
    short* Qc   = (short*)(S + 64 * MB);   // 8MB
    short* AOc  = (short*)(S + 72 * MB);   // 8MB
    float* P0c  = (float*)(S + 32 * MB);   // 16MB (over dead Kc, after attn)
    float* P1c  = (float*)(S + 48 * MB);   // 16MB (over dead VcT)

    add_conv2<<<8192, 256, 0, stream>>>(mem, pos, nullptr, kcb, memb);

    gemm_bt<0,0,1><<<dim3(32, 4), 256, 0, stream>>>(qcb, a1_wqt, nullptr, Qc, M1, 512, 512);
    // fused KV projection; K -> Kc (dense ld 512), V -> VcT transposed
    gemm_bt2vt<<<dim3(64, 8), 256, 0, stream>>>(kcb, memb, a1_wkt, Kc, VcT,
                                                M2, 1024, 512, 512, 512, 512, 11);
    attn_kernel<<<512, 256, 0, stream>>>(Qc, Kc, VcT, AOc,
                                         1024, 2048, 512, 512);
    gemm_bt_sk<1><<<dim3(32, 4, 2), 256, 0, stream>>>(AOc, a1_wot, a1_bo, P0c,
                                                      M1, 512, 512);
    ln_res_kernel<<<2048, 256, 0, stream>>>(P0c, P1c, a1_g, a1_b, resid, nullptr, xf, xb);

    // ---------------- block F1: FFN (writes d_out) ----------------
    short* Hb2  = (short*)(S + 0 * MB);    // 32MB (kcb/memb dead)
    float* P0g  = (float*)(S + 32 * MB);   // 16MB (P0c dead after A1-ln)
    float* P1g  = (float*)(S + 48 * MB);   // 16MB
    gemm_bt<1,1,1><<<dim3(32, 16), 256, 0, stream>>>(xb, f1_w1t, f1_b1, Hb2, M1, 2048, 512);
    gemm_bt_sk<1><<<dim3(32, 4, 2), 256, 0, stream>>>(Hb2, f1_w2t, f1_b2, P0g,
                                                      M1, 512, 2048);
    ln_res_kernel<<<2048, 256, 0, stream>>>(P0g, P1g, f1_g, f1_b, xf, nullptr,
                                            (float*)d_out, nullptr);
}

// Round 12
// 431.226 us; speedup vs baseline: 1.2402x; 1.2402x over previous
//
#include <hip/hip_runtime.h>
#include <stdint.h>
#include <stddef.h>

// ---------------------------------------------------------------- types
typedef __attribute__((ext_vector_type(8))) short short8;
typedef __attribute__((ext_vector_type(4))) short short4v;
typedef __attribute__((ext_vector_type(4))) float floatx4;

#define DEV __device__ __forceinline__

DEV float bf2f(short s) {
    union { float f; uint32_t u; } v;
    v.u = ((uint32_t)(uint16_t)s) << 16;
    return v.f;
}
DEV short f2bf(float f) {
    union { float f; uint32_t u; } v;
    v.f = f;
    uint32_t u = v.u + 0x7FFFu + ((v.u >> 16) & 1u);  // RNE
    return (short)(u >> 16);
}
DEV short f2bf_tr(float f) {           // truncate (1 op) — P matrix only
    union { float f; uint32_t u; } v;
    v.f = f;
    return (short)(v.u >> 16);
}

// ---------------------------------------------------------------- GEMM core
// C(M,N) = A(M,K) @ Bt(N,K)^T ; 128x128 tile, 4 waves, BK=32, dbuf staging.
template<int BIAS, int RELU, int OUTBF>
__global__ __launch_bounds__(256) void gemm_bt(
    const short* __restrict__ A, const short* __restrict__ Bt,
    const float* __restrict__ bias, void* __restrict__ Cout,
    int M, int N, int K)
{
    __shared__ short Alds[2][128 * 32];
    __shared__ short Blds[2][128 * 32];
    const int tid  = threadIdx.x;
    const int wave = tid >> 6, lane = tid & 63;
    const int g = lane >> 4, li = lane & 15;

    const int gx = gridDim.x;
    int flat = blockIdx.y * gx + blockIdx.x;
    const int nwg = gx * gridDim.y;
    flat = (flat & 7) * (nwg >> 3) + (flat >> 3);   // XCD swizzle (nwg%8==0)
    const long bm = (long)(flat % gx) * 128;
    const long bn = (long)(flat / gx) * 128;

    const int wr = (wave >> 1) * 64;
    const int wc = (wave & 1) * 64;
    const int srow = wave * 32 + (lane >> 2);
    const int scol = (lane & 3) * 8;
    const short* Ap = A + (bm + srow) * (long)K + scol;
    const short* Bp = Bt + (bn + srow) * (long)K + scol;

    auto STAGE = [&](int buf, int k0) {
        __builtin_amdgcn_global_load_lds(
            (const __attribute__((address_space(1))) void*)(Ap + k0),
            (__attribute__((address_space(3))) void*)(&Alds[buf][wave * 1024]), 16, 0, 0);
        __builtin_amdgcn_global_load_lds(
            (const __attribute__((address_space(1))) void*)(Ap + (long)16 * K + k0),
            (__attribute__((address_space(3))) void*)(&Alds[buf][wave * 1024 + 512]), 16, 0, 0);
        __builtin_amdgcn_global_load_lds(
            (const __attribute__((address_space(1))) void*)(Bp + k0),
            (__attribute__((address_space(3))) void*)(&Blds[buf][wave * 1024]), 16, 0, 0);
        __builtin_amdgcn_global_load_lds(
            (const __attribute__((address_space(1))) void*)(Bp + (long)16 * K + k0),
            (__attribute__((address_space(3))) void*)(&Blds[buf][wave * 1024 + 512]), 16, 0, 0);
    };

    floatx4 acc[4][4];
#pragma unroll
    for (int i = 0; i < 4; i++)
#pragma unroll
        for (int j = 0; j < 4; j++) acc[i][j] = (floatx4){0.f, 0.f, 0.f, 0.f};

    STAGE(0, 0);
    __syncthreads();
    int cur = 0;
    for (int k0 = 0; k0 < K; k0 += 32) {
        if (k0 + 32 < K) STAGE(cur ^ 1, k0 + 32);

        short8 af[4], bfr[4];
#pragma unroll
        for (int mi = 0; mi < 4; mi++)
            af[mi] = *(const short8*)(&Alds[cur][(wr + mi * 16 + li) * 32 + g * 8]);
#pragma unroll
        for (int ni = 0; ni < 4; ni++)
            bfr[ni] = *(const short8*)(&Blds[cur][(wc + ni * 16 + li) * 32 + g * 8]);
#pragma unroll
        for (int mi = 0; mi < 4; mi++)
#pragma unroll
            for (int ni = 0; ni < 4; ni++)
                acc[mi][ni] = __builtin_amdgcn_mfma_f32_16x16x32_bf16(
                    af[mi], bfr[ni], acc[mi][ni], 0, 0, 0);

        __syncthreads();
        cur ^= 1;
    }

    float* Cf = (float*)Cout;
    short* Cb = (short*)Cout;
#pragma unroll
    for (int mi = 0; mi < 4; mi++) {
#pragma unroll
        for (int ni = 0; ni < 4; ni++) {
            const long col = bn + wc + ni * 16 + li;
            const float bv = BIAS ? bias[col] : 0.f;
#pragma unroll
            for (int i = 0; i < 4; i++) {
                const long row = bm + wr + mi * 16 + g * 4 + i;
                float v = acc[mi][ni][i] + bv;
                if (RELU) v = fmaxf(v, 0.f);
                if (OUTBF) Cb[row * N + col] = f2bf(v);
                else       Cf[row * N + col] = v;
            }
        }
    }
}

// Dual-A + V^T-epilogue variant.
// A = A0 for cols < nsplit, A1 otherwise. Cols < vtoff are written to C
// (bf16, leading dim ldc). Cols >= vtoff are the V projection: written ONLY
// transposed into VT[b][d][key] (key = row % NKv, b = row >> nkvlog,
// d = col - vtoff). Lane's 4 acc values = 4 consecutive keys -> short4v store.
__global__ __launch_bounds__(256) void gemm_bt2vt(
    const short* __restrict__ A0, const short* __restrict__ A1,
    const short* __restrict__ Bt, short* __restrict__ Cout,
    short* __restrict__ VT,
    int M, int N, int K, int nsplit, int ldc, int vtoff, int nkvlog)
{
    __shared__ short Alds[2][128 * 32];
    __shared__ short Blds[2][128 * 32];
    const int tid  = threadIdx.x;
    const int wave = tid >> 6, lane = tid & 63;
    const int g = lane >> 4, li = lane & 15;

    const int gx = gridDim.x;
    int flat = blockIdx.y * gx + blockIdx.x;
    const int nwg = gx * gridDim.y;
    flat = (flat & 7) * (nwg >> 3) + (flat >> 3);
    const long bm = (long)(flat % gx) * 128;
    const long bn = (long)(flat / gx) * 128;

    const int wr = (wave >> 1) * 64;
    const int wc = (wave & 1) * 64;
    const int srow = wave * 32 + (lane >> 2);
    const int scol = (lane & 3) * 8;
    const short* A = (bn < nsplit) ? A0 : A1;
    const short* Ap = A + (bm + srow) * (long)K + scol;
    const short* Bp = Bt + (bn + srow) * (long)K + scol;

    auto STAGE = [&](int buf, int k0) {
        __builtin_amdgcn_global_load_lds(
            (const __attribute__((address_space(1))) void*)(Ap + k0),
            (__attribute__((address_space(3))) void*)(&Alds[buf][wave * 1024]), 16, 0, 0);
        __builtin_amdgcn_global_load_lds(
            (const __attribute__((address_space(1))) void*)(Ap + (long)16 * K + k0),
            (__attribute__((address_space(3))) void*)(&Alds[buf][wave * 1024 + 512]), 16, 0, 0);
        __builtin_amdgcn_global_load_lds(
            (const __attribute__((address_space(1))) void*)(Bp + k0),
            (__attribute__((address_space(3))) void*)(&Blds[buf][wave * 1024]), 16, 0, 0);
        __builtin_amdgcn_global_load_lds(
            (const __attribute__((address_space(1))) void*)(Bp + (long)16 * K + k0),
            (__attribute__((address_space(3))) void*)(&Blds[buf][wave * 1024 + 512]), 16, 0, 0);
    };

    floatx4 acc[4][4];
#pragma unroll
    for (int i = 0; i < 4; i++)
#pragma unroll
        for (int j = 0; j < 4; j++) acc[i][j] = (floatx4){0.f, 0.f, 0.f, 0.f};

    STAGE(0, 0);
    __syncthreads();
    int cur = 0;
    for (int k0 = 0; k0 < K; k0 += 32) {
        if (k0 + 32 < K) STAGE(cur ^ 1, k0 + 32);
        short8 af[4], bfr[4];
#pragma unroll
        for (int mi = 0; mi < 4; mi++)
            af[mi] = *(const short8*)(&Alds[cur][(wr + mi * 16 + li) * 32 + g * 8]);
#pragma unroll
        for (int ni = 0; ni < 4; ni++)
            bfr[ni] = *(const short8*)(&Blds[cur][(wc + ni * 16 + li) * 32 + g * 8]);
#pragma unroll
        for (int mi = 0; mi < 4; mi++)
#pragma unroll
            for (int ni = 0; ni < 4; ni++)
                acc[mi][ni] = __builtin_amdgcn_mfma_f32_16x16x32_bf16(
                    af[mi], bfr[ni], acc[mi][ni], 0, 0, 0);
        __syncthreads();
        cur ^= 1;
    }

    if (bn < vtoff) {
        // normal C write (bf16, ld = ldc)
#pragma unroll
        for (int mi = 0; mi < 4; mi++)
#pragma unroll
            for (int ni = 0; ni < 4; ni++) {
                const long col = bn + wc + ni * 16 + li;
#pragma unroll
                for (int i = 0; i < 4; i++) {
                    const long row = bm + wr + mi * 16 + g * 4 + i;
                    Cout[row * ldc + col] = f2bf(acc[mi][ni][i]);
                }
            }
    } else {
        // V^T write: VT[(b*512 + d)*NKv + key], 4 consecutive keys per frag
        const int mask = (1 << nkvlog) - 1;
#pragma unroll
        for (int mi = 0; mi < 4; mi++) {
            const int row0 = (int)(bm + wr + mi * 16 + g * 4);
            const int bb = row0 >> nkvlog;
            const int key0 = row0 & mask;
#pragma unroll
            for (int ni = 0; ni < 4; ni++) {
                const int d = (int)(bn + wc + ni * 16 + li) - vtoff;
                short4v o = { f2bf(acc[mi][ni][0]), f2bf(acc[mi][ni][1]),
                              f2bf(acc[mi][ni][2]), f2bf(acc[mi][ni][3]) };
                *(short4v*)(VT + ((long)(bb * 512 + d) << nkvlog) + key0) = o;
            }
        }
    }
}

// Split-K=2 variant: blockIdx.z picks K-half; writes f32 partial z (M*N each).
// bias (if BIAS) applied in partial 0 only. Partials summed in ln_res.
template<int BIAS>
__global__ __launch_bounds__(256) void gemm_bt_sk(
    const short* __restrict__ A, const short* __restrict__ Bt,
    const float* __restrict__ bias, float* __restrict__ Cout,
    int M, int N, int K)
{
    __shared__ short Alds[2][128 * 32];
    __shared__ short Blds[2][128 * 32];
    const int tid  = threadIdx.x;
    const int wave = tid >> 6, lane = tid & 63;
    const int g = lane >> 4, li = lane & 15;
    const int z = blockIdx.z;
    const int Kh = K >> 1;

    const int gx = gridDim.x;
    int flat = blockIdx.y * gx + blockIdx.x;
    const int nwg = gx * gridDim.y;
    flat = (flat & 7) * (nwg >> 3) + (flat >> 3);
    const long bm = (long)(flat % gx) * 128;
    const long bn = (long)(flat / gx) * 128;

    const int wr = (wave >> 1) * 64;
    const int wc = (wave & 1) * 64;
    const int srow = wave * 32 + (lane >> 2);
    const int scol = (lane & 3) * 8;
    const short* Ap = A + (bm + srow) * (long)K + scol + (long)z * Kh;
    const short* Bp = Bt + (bn + srow) * (long)K + scol + (long)z * Kh;
    float* C = Cout + (long)z * M * N;

    auto STAGE = [&](int buf, int k0) {
        __builtin_amdgcn_global_load_lds(
            (const __attribute__((address_space(1))) void*)(Ap + k0),
            (__attribute__((address_space(3))) void*)(&Alds[buf][wave * 1024]), 16, 0, 0);
        __builtin_amdgcn_global_load_lds(
            (const __attribute__((address_space(1))) void*)(Ap + (long)16 * K + k0),
            (__attribute__((address_space(3))) void*)(&Alds[buf][wave * 1024 + 512]), 16, 0, 0);
        __builtin_amdgcn_global_load_lds(
            (const __attribute__((address_space(1))) void*)(Bp + k0),
            (__attribute__((address_space(3))) void*)(&Blds[buf][wave * 1024]), 16, 0, 0);
        __builtin_amdgcn_global_load_lds(
            (const __attribute__((address_space(1))) void*)(Bp + (long)16 * K + k0),
            (__attribute__((address_space(3))) void*)(&Blds[buf][wave * 1024 + 512]), 16, 0, 0);
    };

    floatx4 acc[4][4];
#pragma unroll
    for (int i = 0; i < 4; i++)
#pragma unroll
        for (int j = 0; j < 4; j++) acc[i][j] = (floatx4){0.f, 0.f, 0.f, 0.f};

    STAGE(0, 0);
    __syncthreads();
    int cur = 0;
    for (int k0 = 0; k0 < Kh; k0 += 32) {
        if (k0 + 32 < Kh) STAGE(cur ^ 1, k0 + 32);
        short8 af[4], bfr[4];
#pragma unroll
        for (int mi = 0; mi < 4; mi++)
            af[mi] = *(const short8*)(&Alds[cur][(wr + mi * 16 + li) * 32 + g * 8]);
#pragma unroll
        for (int ni = 0; ni < 4; ni++)
            bfr[ni] = *(const short8*)(&Blds[cur][(wc + ni * 16 + li) * 32 + g * 8]);
#pragma unroll
        for (int mi = 0; mi < 4; mi++)
#pragma unroll
            for (int ni = 0; ni < 4; ni++)
                acc[mi][ni] = __builtin_amdgcn_mfma_f32_16x16x32_bf16(
                    af[mi], bfr[ni], acc[mi][ni], 0, 0, 0);
        __syncthreads();
        cur ^= 1;
    }

#pragma unroll
    for (int mi = 0; mi < 4; mi++)
#pragma unroll
        for (int ni = 0; ni < 4; ni++) {
            const long col = bn + wc + ni * 16 + li;
            const float bv = (BIAS && z == 0) ? bias[col] : 0.f;
#pragma unroll
            for (int i = 0; i < 4; i++) {
                const long row = bm + wr + mi * 16 + g * 4 + i;
                C[row * N + col] = acc[mi][ni][i] + bv;
            }
        }
}

// ---------------------------------------------------------------- attention
// KT=32, 32 q/wave, T14 async staging, static-max softmax, LD=68/LDP=36,
// XCD-locality decode. Frozen: KT=64 regressed twice (R2, R10).
__global__ __launch_bounds__(256) void attn_kernel(
    const short* __restrict__ Qg, const short* __restrict__ Kg,
    const short* __restrict__ VTg, short* __restrict__ Og,
    int NQ, int NK, int ldq, int ldk)
{
    constexpr int LD = 68, LDP = 36;
    __shared__ short Klds[32 * LD];       // [key][d]
    __shared__ short Vlds[64 * LD];       // [d][key]
    __shared__ short Plds[4][32 * LDP];   // per-wave [q][key], 32 q rows

    const int tid = threadIdx.x;
    const int wave = tid >> 6, lane = tid & 63;
    const int g = lane >> 4, li = lane & 15;

    const int nqb = NQ >> 7;
    const int i   = blockIdx.x;
    const int xcd = i & 7;
    const int t   = i >> 3;
    const int c   = t % nqb;
    const int gh  = t / nqb;
    const int grp = xcd + 8 * gh;         // 0..63
    const int b   = grp >> 3, h = grp & 7;
    const int q0  = c * 128 + wave * 32;

    const short* qptrA = Qg + ((long)(b * NQ + q0 + li) * ldq + h * 64);
    const short* qptrB = qptrA + (long)16 * ldq;
    short8 qfA[2], qfB[2];
#pragma unroll
    for (int f = 0; f < 2; f++) {
        short8 ta = *(const short8*)(qptrA + f * 32 + g * 8);
        short8 tb = *(const short8*)(qptrB + f * 32 + g * 8);
#pragma unroll
        for (int ii = 0; ii < 8; ii++) {
            ta[ii] = f2bf(bf2f(ta[ii]) * 0.18033688011112042f);
            tb[ii] = f2bf(bf2f(tb[ii]) * 0.18033688011112042f);
        }
        qfA[f] = ta; qfB[f] = tb;
    }

    floatx4 accA[4], accB[4];
#pragma unroll
    for (int s = 0; s < 4; s++) {
        accA[s] = (floatx4){0.f, 0.f, 0.f, 0.f};
        accB[s] = (floatx4){0.f, 0.f, 0.f, 0.f};
    }
    float lsumA = 0.f, lsumB = 0.f;

    const int skey = tid >> 3, sdc = (tid & 7) * 8;  // K staging: 32 keys x 64 d
    const int svd = tid >> 2, svk = (tid & 3) * 8;   // VT staging: 64 d x 32 keys
    const short* kp = Kg + (long)b * NK * ldk + h * 64 + (long)skey * ldk + sdc;
    const short* vp = VTg + ((long)(b * 512 + h * 64 + svd)) * NK + svk;

    short8 kreg = *(const short8*)kp;  kp += (long)32 * ldk;
    short8 vreg = *(const short8*)vp;  vp += 32;

    for (int kt = 0; kt < NK; kt += 32) {
        __syncthreads();
        *(short8*)(Klds + skey * LD + sdc) = kreg;
        *(short8*)(Vlds + svd * LD + svk) = vreg;
        __syncthreads();
        if (kt + 32 < NK) {
            kreg = *(const short8*)kp;  kp += (long)32 * ldk;
            vreg = *(const short8*)vp;  vp += 32;
        }

        // S^T subtiles: lane holds S[key = sub*16 + 4g + i][q = li (A) / 16+li (B)]
        floatx4 sA0 = (floatx4){0.f, 0.f, 0.f, 0.f};
        floatx4 sA1 = (floatx4){0.f, 0.f, 0.f, 0.f};
        floatx4 sB0 = (floatx4){0.f, 0.f, 0.f, 0.f};
        floatx4 sB1 = (floatx4){0.f, 0.f, 0.f, 0.f};
        {
            short8 k00 = *(const short8*)(Klds + li * LD + g * 8);
            short8 k01 = *(const short8*)(Klds + li * LD + 32 + g * 8);
            short8 k10 = *(const short8*)(Klds + (16 + li) * LD + g * 8);
            short8 k11 = *(const short8*)(Klds + (16 + li) * LD + 32 + g * 8);
            sA0 = __builtin_amdgcn_mfma_f32_16x16x32_bf16(k00, qfA[0], sA0, 0, 0, 0);
            sA0 = __builtin_amdgcn_mfma_f32_16x16x32_bf16(k01, qfA[1], sA0, 0, 0, 0);
            sA1 = __builtin_amdgcn_mfma_f32_16x16x32_bf16(k10, qfA[0], sA1, 0, 0, 0);
            sA1 = __builtin_amdgcn_mfma_f32_16x16x32_bf16(k11, qfA[1], sA1, 0, 0, 0);
            sB0 = __builtin_amdgcn_mfma_f32_16x16x32_bf16(k00, qfB[0], sB0, 0, 0, 0);
            sB0 = __builtin_amdgcn_mfma_f32_16x16x32_bf16(k01, qfB[1], sB0, 0, 0, 0);
            sB1 = __builtin_amdgcn_mfma_f32_16x16x32_bf16(k10, qfB[0], sB1, 0, 0, 0);
            sB1 = __builtin_amdgcn_mfma_f32_16x16x32_bf16(k11, qfB[1], sB1, 0, 0, 0);
        }

        // static-max softmax: p = exp2(S)
        const float a0 = exp2f(sA0[0]), a1 = exp2f(sA0[1]);
        const float a2 = exp2f(sA0[2]), a3 = exp2f(sA0[3]);
        const float a4 = exp2f(sA1[0]), a5 = exp2f(sA1[1]);
        const float a6 = exp2f(sA1[2]), a7 = exp2f(sA1[3]);
        lsumA += ((a0 + a1) + (a2 + a3)) + ((a4 + a5) + (a6 + a7));
        const float b0 = exp2f(sB0[0]), b1 = exp2f(sB0[1]);
        const float b2 = exp2f(sB0[2]), b3 = exp2f(sB0[3]);
        const float b4 = exp2f(sB1[0]), b5 = exp2f(sB1[1]);
        const float b6 = exp2f(sB1[2]), b7 = exp2f(sB1[3]);
        lsumB += ((b0 + b1) + (b2 + b3)) + ((b4 + b5) + (b6 + b7));

        short4v pa0 = { f2bf_tr(a0), f2bf_tr(a1), f2bf_tr(a2), f2bf_tr(a3) };
        short4v pa1 = { f2bf_tr(a4), f2bf_tr(a5), f2bf_tr(a6), f2bf_tr(a7) };
        short4v pb0 = { f2bf_tr(b0), f2bf_tr(b1), f2bf_tr(b2), f2bf_tr(b3) };
        short4v pb1 = { f2bf_tr(b4), f2bf_tr(b5), f2bf_tr(b6), f2bf_tr(b7) };
        *(short4v*)(Plds[wave] + li * LDP + g * 4) = pa0;
        *(short4v*)(Plds[wave] + li * LDP + 16 + g * 4) = pa1;
        *(short4v*)(Plds[wave] + (16 + li) * LDP + g * 4) = pb0;
        *(short4v*)(Plds[wave] + (16 + li) * LDP + 16 + g * 4) = pb1;
        short8 pfA = *(const short8*)(Plds[wave] + li * LDP + g * 8);
        short8 pfB = *(const short8*)(Plds[wave] + (16 + li) * LDP + g * 8);

        // O^T slices: acc[s] += VT_slice(16d x 32k) . P^T(32k x 16q)
#pragma unroll
        for (int s = 0; s < 4; s++) {
            short8 vf = *(const short8*)(Vlds + (s * 16 + li) * LD + g * 8);
            accA[s] = __builtin_amdgcn_mfma_f32_16x16x32_bf16(vf, pfA, accA[s], 0, 0, 0);
            accB[s] = __builtin_amdgcn_mfma_f32_16x16x32_bf16(vf, pfB, accB[s], 0, 0, 0);
        }
    }

    lsumA += __shfl_xor(lsumA, 16);
    lsumA += __shfl_xor(lsumA, 32);
    lsumB += __shfl_xor(lsumB, 16);
    lsumB += __shfl_xor(lsumB, 32);
    const float invA = 1.f / lsumA;
    const float invB = 1.f / lsumB;
    short* optrA = Og + ((long)(b * NQ + q0 + li) * 512 + h * 64);
    short* optrB = optrA + (long)16 * 512;
#pragma unroll
    for (int s = 0; s < 4; s++) {
        short4v oa = { f2bf(accA[s][0] * invA), f2bf(accA[s][1] * invA),
                       f2bf(accA[s][2] * invA), f2bf(accA[s][3] * invA) };
        short4v ob = { f2bf(accB[s][0] * invB), f2bf(accB[s][1] * invB),
                       f2bf(accB[s][2] * invB), f2bf(accB[s][3] * invB) };
        *(short4v*)(optrA + s * 16 + g * 4) = oa;
        *(short4v*)(optrB + s * 16 + g * 4) = ob;
    }
}

// ---------------------------------------------------------------- small kernels
__global__ __launch_bounds__(256) void add_conv2(
    const float* __restrict__ a, const float* __restrict__ b,
    float* __restrict__ of, short* __restrict__ ob1, short* __restrict__ ob2)
{
    const long i = (long)(blockIdx.x * 256 + threadIdx.x) * 4;
    const float4 va = *(const float4*)(a + i);
    float4 vs = va;
    if (b) {
        const float4 vb = *(const float4*)(b + i);
        vs.x += vb.x; vs.y += vb.y; vs.z += vb.z; vs.w += vb.w;
    }
    if (of) *(float4*)(of + i) = vs;
    short4v o1 = { f2bf(vs.x), f2bf(vs.y), f2bf(vs.z), f2bf(vs.w) };
    *(short4v*)(ob1 + i) = o1;
    if (ob2) {
        short4v o2 = { f2bf(va.x), f2bf(va.y), f2bf(va.z), f2bf(va.w) };
        *(short4v*)(ob2 + i) = o2;
    }
}

// y = LayerNorm(X [+X2])*g + b + res [+ postadd]; outF f32, outB bf16 (opt)
__global__ __launch_bounds__(256) void ln_res_kernel(
    const float* __restrict__ X, const float* __restrict__ X2,
    const float* __restrict__ gam, const float* __restrict__ bet,
    const float* __restrict__ res, const float* __restrict__ postadd,
    float* __restrict__ outF, short* __restrict__ outB)
{
    const int row = blockIdx.x * 4 + (threadIdx.x >> 6);
    const int lane = threadIdx.x & 63;
    const long base = (long)row * 512 + lane * 8;
    float x[8];
    *(float4*)(x) = *(const float4*)(X + base);
    *(float4*)(x + 4) = *(const float4*)(X + base + 4);
    if (X2) {
        float x2[8];
        *(float4*)(x2) = *(const float4*)(X2 + base);
        *(float4*)(x2 + 4) = *(const float4*)(X2 + base + 4);
#pragma unroll
        for (int i = 0; i < 8; i++) x[i] += x2[i];
    }
    float s = x[0] + x[1] + x[2] + x[3] + x[4] + x[5] + x[6] + x[7];
#pragma unroll
    for (int o = 1; o < 64; o <<= 1) s += __shfl_xor(s, o);
    const float mu = s * (1.0f / 512.0f);
    float vs = 0.f;
#pragma unroll
    for (int i = 0; i < 8; i++) { const float d = x[i] - mu; vs += d * d; }
#pragma unroll
    for (int o = 1; o < 64; o <<= 1) vs += __shfl_xor(vs, o);
    const float rs = rsqrtf(vs * (1.0f / 512.0f) + 1e-5f);

    float gv[8], bv[8], rv[8];
    *(float4*)(gv) = *(const float4*)(gam + lane * 8);
    *(float4*)(gv + 4) = *(const float4*)(gam + lane * 8 + 4);
    *(float4*)(bv) = *(const float4*)(bet + lane * 8);
    *(float4*)(bv + 4) = *(const float4*)(bet + lane * 8 + 4);
    *(float4*)(rv) = *(const float4*)(res + base);
    *(float4*)(rv + 4) = *(const float4*)(res + base + 4);

    float y[8];
#pragma unroll
    for (int i = 0; i < 8; i++) y[i] = (x[i] - mu) * rs * gv[i] + bv[i] + rv[i];
    if (postadd) {
        float pv[8];
        *(float4*)(pv) = *(const float4*)(postadd + base);
        *(float4*)(pv + 4) = *(const float4*)(postadd + base + 4);
#pragma unroll
        for (int i = 0; i < 8; i++) y[i] += pv[i];
    }
    *(float4*)(outF + base) = *(float4*)(y);
    *(float4*)(outF + base + 4) = *(float4*)(y + 4);
    if (outB) {
        short8 ob;
#pragma unroll
        for (int i = 0; i < 8; i++) ob[i] = f2bf(y[i]);
        *(short8*)(outB + base) = ob;
    }
}

// batched W (K,N) f32 -> Wt (N,K) bf16; blockIdx.z selects source/dest
__global__ __launch_bounds__(256) void wtrans8(
    const float* __restrict__ w0, const float* __restrict__ w1,
    const float* __restrict__ w2, const float* __restrict__ w3,
    const float* __restrict__ w4, const float* __restrict__ w5,
    const float* __restrict__ w6, const float* __restrict__ w7,
    short* __restrict__ o0, short* __restrict__ o1,
    short* __restrict__ o2, short* __restrict__ o3,
    short* __restrict__ o4, short* __restrict__ o5,
    short* __restrict__ o6, short* __restrict__ o7,
    int K, int N)
{
    const float* Ws[8] = {w0, w1, w2, w3, w4, w5, w6, w7};
    short* Os[8] = {o0, o1, o2, o3, o4, o5, o6, o7};
    const float* W = Ws[blockIdx.z];
    short* Wt = Os[blockIdx.z];
    __shared__ short t[32][33];
    const int n0 = blockIdx.x * 32, k0 = blockIdx.y * 32;
    const int tx = threadIdx.x & 31, ty = threadIdx.x >> 5;
    for (int r = ty; r < 32; r += 8)
        t[r][tx] = f2bf(W[(long)(k0 + r) * N + n0 + tx]);
    __syncthreads();
    for (int r = ty; r < 32; r += 8)
        Wt[(long)(n0 + r) * K + k0 + tx] = t[tx][r];
}

// ---------------------------------------------------------------- launch
extern "C" void kernel_launch(void* const* d_in, const int* in_sizes, int n_in,
                              void* d_out, int out_size, void* d_ws, size_t ws_size,
                              hipStream_t stream)
{
    (void)in_sizes; (void)n_in; (void)out_size; (void)ws_size;
    const float* tgt   = (const float*)d_in[0];
    const float* mem   = (const float*)d_in[1];
    const float* pos   = (const float*)d_in[2];
    const float* qpos  = (const float*)d_in[3];
    const float* a0_wq = (const float*)d_in[4];
    const float* a0_wk = (const float*)d_in[5];
    const float* a0_wv = (const float*)d_in[6];
    const float* a0_wo = (const float*)d_in[7];
    const float* a0_bo = (const float*)d_in[8];
    const float* a0_g  = (const float*)d_in[9];
    const float* a0_b  = (const float*)d_in[10];
    const float* f0_w1 = (const float*)d_in[11];
    const float* f0_b1 = (const float*)d_in[12];
    const float* f0_w2 = (const float*)d_in[13];
    const float* f0_b2 = (const float*)d_in[14];
    const float* f0_g  = (const float*)d_in[15];
    const float* f0_b  = (const float*)d_in[16];
    const float* a1_wq = (const float*)d_in[17];
    const float* a1_wk = (const float*)d_in[18];
    const float* a1_wv = (const float*)d_in[19];
    const float* a1_wo = (const float*)d_in[20];
    const float* a1_bo = (const float*)d_in[21];
    const float* a1_g  = (const float*)d_in[22];
    const float* a1_b  = (const float*)d_in[23];
    const float* f1_w1 = (const float*)d_in[24];
    const float* f1_b1 = (const float*)d_in[25];
    const float* f1_w2 = (const float*)d_in[26];
    const float* f1_b2 = (const float*)d_in[27];
    const float* f1_g  = (const float*)d_in[28];
    const float* f1_b  = (const float*)d_in[29];

    const int M1 = 8 * 1024;   // 8192 query rows
    const int M2 = 8 * 2048;   // 16384 memory rows
    const size_t MB = 1ull << 20;
    char* ws = (char*)d_ws;

    float* resid = (float*)(ws + 0 * MB);       // 16MB
    float* xf    = (float*)(ws + 16 * MB);      // 16MB
    short* xb    = (short*)(ws + 32 * MB);      // 8MB
    short* wb    = (short*)(ws + 40 * MB);      // 12MB bf16 W^T bank
    short* a0_wqt = wb;            short* a0_wkt = wb + 262144;   // Wq^T||Wk^T||Wv^T
    short* a0_wvt = wb + 524288;   short* a0_wot = wb + 786432;
    short* f0_w1t = wb + 1048576;  short* f0_w2t = wb + 2097152;
    short* a1_wqt = wb + 3145728;  short* a1_wkt = wb + 3407872;   // Wk^T||Wv^T
    short* a1_wvt = wb + 3670016;  short* a1_wot = wb + 3932160;
    short* f1_w1t = wb + 4194304;  short* f1_w2t = wb + 5242880;
    char* S = ws + 56 * MB;                      // stage scratch (max used: +88MB)

    wtrans8<<<dim3(16, 16, 8), 256, 0, stream>>>(
        a0_wq, a0_wk, a0_wv, a0_wo, a1_wq, a1_wk, a1_wv, a1_wo,
        a0_wqt, a0_wkt, a0_wvt, a0_wot, a1_wqt, a1_wkt, a1_wvt, a1_wot, 512, 512);
    wtrans8<<<dim3(64, 16, 2), 256, 0, stream>>>(
        f0_w1, f1_w1, nullptr, nullptr, nullptr, nullptr, nullptr, nullptr,
        f0_w1t, f1_w1t, nullptr, nullptr, nullptr, nullptr, nullptr, nullptr, 512, 2048);
    wtrans8<<<dim3(16, 64, 2), 256, 0, stream>>>(
        f0_w2, f1_w2, nullptr, nullptr, nullptr, nullptr, nullptr, nullptr,
        f0_w2t, f1_w2t, nullptr, nullptr, nullptr, nullptr, nullptr, nullptr, 2048, 512);

    // ---------------- block A0: self-attention ----------------
    short* QKs  = (short*)(S + 0 * MB);    // 16MB: [8192][1024] = Q||K (ld 1024)
    short* VsT  = (short*)(S + 16 * MB);   // 8MB:  [8][512][1024] V^T
    short* AOs  = (short*)(S + 24 * MB);   // 8MB
    float* P0a  = (float*)(S + 32 * MB);   // 16MB
    float* P1a  = (float*)(S + 48 * MB);   // 16MB
    short* q0b  = (short*)(S + 64 * MB);   // 8MB
    short* tgtb = (short*)(S + 72 * MB);   // 8MB

    add_conv2<<<4096, 256, 0, stream>>>(tgt, qpos, resid, q0b, tgtb);

    // fused QKV projection; V section written directly transposed to VsT
    gemm_bt2vt<<<dim3(64, 12), 256, 0, stream>>>(q0b, tgtb, a0_wqt, QKs, VsT,
                                                 M1, 1536, 512, 1024, 1024, 1024, 10);
    attn_kernel<<<512, 256, 0, stream>>>(QKs, QKs + 512, VsT, AOs,
                                         1024, 1024, 1024, 1024);
    gemm_bt_sk<1><<<dim3(64, 4, 2), 256, 0, stream>>>(AOs, a0_wot, a0_bo, P0a,
                                                      M1, 512, 512);
    ln_res_kernel<<<2048, 256, 0, stream>>>(P0a, P1a, a0_g, a0_b, resid, nullptr, xf, xb);

    // ---------------- block F0: FFN ----------------
    short* Hb  = (short*)(S + 0 * MB);     // 32MB (QKs/VsT/AOs dead)
    float* P0f = (float*)(S + 32 * MB);    // 16MB (over dead P0a)
    float* P1f = (float*)(S + 48 * MB);    // 16MB (over dead P1a)
    short* qcb = (short*)(S + 80 * MB);    // 8MB (A1 q input, written by ln)
    gemm_bt<1,1,1><<<dim3(64, 16), 256, 0, stream>>>(xb, f0_w1t, f0_b1, Hb, M1, 2048, 512);
    gemm_bt_sk<1><<<dim3(64, 4, 2), 256, 0, stream>>>(Hb, f0_w2t, f0_b2, P0f,
                                                      M1, 512, 2048);
    // y = LN(P0+P1)+xf ; resid = y+qpos (f32), qcb = bf16(y+qpos)
    ln_res_kernel<<<2048, 256, 0, stream>>>(P0f, P1f, f0_g, f0_b, xf, qpos, resid, qcb);

    // ---------------- block A1: cross-attention ----------------
    // Lifetimes: Hb dead after FFN2-sk; P0f/P1f dead after F0-ln; q0b/tgtb dead.
    // Kc/VcT dead after attn -> P0c/P1c overwrite them.
    short* kcb  = (short*)(S + 0 * MB);    // 16MB (over dead Hb)
    short* memb = (short*)(S + 16 * MB);   // 16MB
    short* Kc   = (short*)(S + 32 * MB);   // 16MB: [16384][512] dense K
    short* VcT  = (short*)(S + 48 * MB);   // 16MB: [8][512][2048] V^T
    short* Qc   = (short*)(S + 64 * MB);   // 8MB
    short* AOc  = (short*)(S + 72 * MB);   // 8MB
    float* P0c  = (float*)(S + 32 * MB);   // 16MB (over dead Kc, after attn)
    float* P1c  = (float*)(S + 48 * MB);   // 16MB (over dead VcT)

    add_conv2<<<8192, 256, 0, stream>>>(mem, pos, nullptr, kcb, memb);

    gemm_bt<0,0,1><<<dim3(64, 4), 256, 0, stream>>>(qcb, a1_wqt, nullptr, Qc, M1, 512, 512);
    // fused KV projection; K -> Kc (dense ld 512), V -> VcT transposed
    gemm_bt2vt<<<dim3(128, 8), 256, 0, stream>>>(kcb, memb, a1_wkt, Kc, VcT,
                                                 M2, 1024, 512, 512, 512, 512, 11);
    attn_kernel<<<512, 256, 0, stream>>>(Qc, Kc, VcT, AOc,
                                         1024, 2048, 512, 512);
    gemm_bt_sk<1><<<dim3(64, 4, 2), 256, 0, stream>>>(AOc, a1_wot, a1_bo, P0c,
                                                      M1, 512, 512);
    ln_res_kernel<<<2048, 256, 0, stream>>>(P0c, P1c, a1_g, a1_b, resid, nullptr, xf, xb);

    // ---------------- block F1: FFN (writes d_out) ----------------
    short* Hb2  = (short*)(S + 0 * MB);    // 32MB (kcb/memb dead)
    float* P0g  = (float*)(S + 32 * MB);   // 16MB (P0c dead after A1-ln)
    float* P1g  = (float*)(S + 48 * MB);   // 16MB
    gemm_bt<1,1,1><<<dim3(64, 16), 256, 0, stream>>>(xb, f1_w1t, f1_b1, Hb2, M1, 2048, 512);
    gemm_bt_sk<1><<<dim3(64, 4, 2), 256, 0, stream>>>(Hb2, f1_w2t, f1_b2, P0g,
                                                      M1, 512, 2048);
    ln_res_kernel<<<2048, 256, 0, stream>>>(P0g, P1g, f1_g, f1_b, xf, nullptr,
                                            (float*)d_out, nullptr);
}

// Round 13
// 430.942 us; speedup vs baseline: 1.2410x; 1.0007x over previous
//
#include <hip/hip_runtime.h>
#include <stdint.h>
#include <stddef.h>

// ---------------------------------------------------------------- types
typedef __attribute__((ext_vector_type(8))) short short8;
typedef __attribute__((ext_vector_type(4))) short short4v;
typedef __attribute__((ext_vector_type(4))) float floatx4;

#define DEV __device__ __forceinline__

DEV float bf2f(short s) {
    union { float f; uint32_t u; } v;
    v.u = ((uint32_t)(uint16_t)s) << 16;
    return v.f;
}
DEV short f2bf(float f) {
    union { float f; uint32_t u; } v;
    v.f = f;
    uint32_t u = v.u + 0x7FFFu + ((v.u >> 16) & 1u);  // RNE
    return (short)(u >> 16);
}
DEV short f2bf_tr(float f) {           // truncate (1 op) — P matrix only
    union { float f; uint32_t u; } v;
    v.f = f;
    return (short)(v.u >> 16);
}

// ---------------------------------------------------------------- GEMM core
// C(M,N) = A(M,K) @ Bt(N,K)^T ; 128x128 tile, 4 waves, BK=32, dbuf staging.
template<int BIAS, int RELU, int OUTBF>
__global__ __launch_bounds__(256) void gemm_bt(
    const short* __restrict__ A, const short* __restrict__ Bt,
    const float* __restrict__ bias, void* __restrict__ Cout,
    int M, int N, int K)
{
    __shared__ short Alds[2][128 * 32];
    __shared__ short Blds[2][128 * 32];
    const int tid  = threadIdx.x;
    const int wave = tid >> 6, lane = tid & 63;
    const int g = lane >> 4, li = lane & 15;

    const int gx = gridDim.x;
    int flat = blockIdx.y * gx + blockIdx.x;
    const int nwg = gx * gridDim.y;
    flat = (flat & 7) * (nwg >> 3) + (flat >> 3);   // XCD swizzle (nwg%8==0)
    const long bm = (long)(flat % gx) * 128;
    const long bn = (long)(flat / gx) * 128;

    const int wr = (wave >> 1) * 64;
    const int wc = (wave & 1) * 64;
    const int srow = wave * 32 + (lane >> 2);
    const int scol = (lane & 3) * 8;
    const short* Ap = A + (bm + srow) * (long)K + scol;
    const short* Bp = Bt + (bn + srow) * (long)K + scol;

    auto STAGE = [&](int buf, int k0) {
        __builtin_amdgcn_global_load_lds(
            (const __attribute__((address_space(1))) void*)(Ap + k0),
            (__attribute__((address_space(3))) void*)(&Alds[buf][wave * 1024]), 16, 0, 0);
        __builtin_amdgcn_global_load_lds(
            (const __attribute__((address_space(1))) void*)(Ap + (long)16 * K + k0),
            (__attribute__((address_space(3))) void*)(&Alds[buf][wave * 1024 + 512]), 16, 0, 0);
        __builtin_amdgcn_global_load_lds(
            (const __attribute__((address_space(1))) void*)(Bp + k0),
            (__attribute__((address_space(3))) void*)(&Blds[buf][wave * 1024]), 16, 0, 0);
        __builtin_amdgcn_global_load_lds(
            (const __attribute__((address_space(1))) void*)(Bp + (long)16 * K + k0),
            (__attribute__((address_space(3))) void*)(&Blds[buf][wave * 1024 + 512]), 16, 0, 0);
    };

    floatx4 acc[4][4];
#pragma unroll
    for (int i = 0; i < 4; i++)
#pragma unroll
        for (int j = 0; j < 4; j++) acc[i][j] = (floatx4){0.f, 0.f, 0.f, 0.f};

    STAGE(0, 0);
    __syncthreads();
    int cur = 0;
    for (int k0 = 0; k0 < K; k0 += 32) {
        if (k0 + 32 < K) STAGE(cur ^ 1, k0 + 32);

        short8 af[4], bfr[4];
#pragma unroll
        for (int mi = 0; mi < 4; mi++)
            af[mi] = *(const short8*)(&Alds[cur][(wr + mi * 16 + li) * 32 + g * 8]);
#pragma unroll
        for (int ni = 0; ni < 4; ni++)
            bfr[ni] = *(const short8*)(&Blds[cur][(wc + ni * 16 + li) * 32 + g * 8]);
#pragma unroll
        for (int mi = 0; mi < 4; mi++)
#pragma unroll
            for (int ni = 0; ni < 4; ni++)
                acc[mi][ni] = __builtin_amdgcn_mfma_f32_16x16x32_bf16(
                    af[mi], bfr[ni], acc[mi][ni], 0, 0, 0);

        __syncthreads();
        cur ^= 1;
    }

    float* Cf = (float*)Cout;
    short* Cb = (short*)Cout;
#pragma unroll
    for (int mi = 0; mi < 4; mi++) {
#pragma unroll
        for (int ni = 0; ni < 4; ni++) {
            const long col = bn + wc + ni * 16 + li;
            const float bv = BIAS ? bias[col] : 0.f;
#pragma unroll
            for (int i = 0; i < 4; i++) {
                const long row = bm + wr + mi * 16 + g * 4 + i;
                float v = acc[mi][ni][i] + bv;
                if (RELU) v = fmaxf(v, 0.f);
                if (OUTBF) Cb[row * N + col] = f2bf(v);
                else       Cf[row * N + col] = v;
            }
        }
    }
}

// Dual-A + V^T-epilogue variant.
// A = A0 for cols < nsplit, A1 otherwise. Cols < vtoff are written to C
// (bf16, leading dim ldc). Cols >= vtoff are the V projection: written ONLY
// transposed into VT[b][d][key] (key = row % NKv, b = row >> nkvlog,
// d = col - vtoff). Lane's 4 acc values = 4 consecutive keys -> short4v store.
__global__ __launch_bounds__(256) void gemm_bt2vt(
    const short* __restrict__ A0, const short* __restrict__ A1,
    const short* __restrict__ Bt, short* __restrict__ Cout,
    short* __restrict__ VT,
    int M, int N, int K, int nsplit, int ldc, int vtoff, int nkvlog)
{
    __shared__ short Alds[2][128 * 32];
    __shared__ short Blds[2][128 * 32];
    const int tid  = threadIdx.x;
    const int wave = tid >> 6, lane = tid & 63;
    const int g = lane >> 4, li = lane & 15;

    const int gx = gridDim.x;
    int flat = blockIdx.y * gx + blockIdx.x;
    const int nwg = gx * gridDim.y;
    flat = (flat & 7) * (nwg >> 3) + (flat >> 3);
    const long bm = (long)(flat % gx) * 128;
    const long bn = (long)(flat / gx) * 128;

    const int wr = (wave >> 1) * 64;
    const int wc = (wave & 1) * 64;
    const int srow = wave * 32 + (lane >> 2);
    const int scol = (lane & 3) * 8;
    const short* A = (bn < nsplit) ? A0 : A1;
    const short* Ap = A + (bm + srow) * (long)K + scol;
    const short* Bp = Bt + (bn + srow) * (long)K + scol;

    auto STAGE = [&](int buf, int k0) {
        __builtin_amdgcn_global_load_lds(
            (const __attribute__((address_space(1))) void*)(Ap + k0),
            (__attribute__((address_space(3))) void*)(&Alds[buf][wave * 1024]), 16, 0, 0);
        __builtin_amdgcn_global_load_lds(
            (const __attribute__((address_space(1))) void*)(Ap + (long)16 * K + k0),
            (__attribute__((address_space(3))) void*)(&Alds[buf][wave * 1024 + 512]), 16, 0, 0);
        __builtin_amdgcn_global_load_lds(
            (const __attribute__((address_space(1))) void*)(Bp + k0),
            (__attribute__((address_space(3))) void*)(&Blds[buf][wave * 1024]), 16, 0, 0);
        __builtin_amdgcn_global_load_lds(
            (const __attribute__((address_space(1))) void*)(Bp + (long)16 * K + k0),
            (__attribute__((address_space(3))) void*)(&Blds[buf][wave * 1024 + 512]), 16, 0, 0);
    };

    floatx4 acc[4][4];
#pragma unroll
    for (int i = 0; i < 4; i++)
#pragma unroll
        for (int j = 0; j < 4; j++) acc[i][j] = (floatx4){0.f, 0.f, 0.f, 0.f};

    STAGE(0, 0);
    __syncthreads();
    int cur = 0;
    for (int k0 = 0; k0 < K; k0 += 32) {
        if (k0 + 32 < K) STAGE(cur ^ 1, k0 + 32);
        short8 af[4], bfr[4];
#pragma unroll
        for (int mi = 0; mi < 4; mi++)
            af[mi] = *(const short8*)(&Alds[cur][(wr + mi * 16 + li) * 32 + g * 8]);
#pragma unroll
        for (int ni = 0; ni < 4; ni++)
            bfr[ni] = *(const short8*)(&Blds[cur][(wc + ni * 16 + li) * 32 + g * 8]);
#pragma unroll
        for (int mi = 0; mi < 4; mi++)
#pragma unroll
            for (int ni = 0; ni < 4; ni++)
                acc[mi][ni] = __builtin_amdgcn_mfma_f32_16x16x32_bf16(
                    af[mi], bfr[ni], acc[mi][ni], 0, 0, 0);
        __syncthreads();
        cur ^= 1;
    }

    if (bn < vtoff) {
        // normal C write (bf16, ld = ldc)
#pragma unroll
        for (int mi = 0; mi < 4; mi++)
#pragma unroll
            for (int ni = 0; ni < 4; ni++) {
                const long col = bn + wc + ni * 16 + li;
#pragma unroll
                for (int i = 0; i < 4; i++) {
                    const long row = bm + wr + mi * 16 + g * 4 + i;
                    Cout[row * ldc + col] = f2bf(acc[mi][ni][i]);
                }
            }
    } else {
        // V^T write: VT[(b*512 + d)*NKv + key], 4 consecutive keys per frag
        const int mask = (1 << nkvlog) - 1;
#pragma unroll
        for (int mi = 0; mi < 4; mi++) {
            const int row0 = (int)(bm + wr + mi * 16 + g * 4);
            const int bb = row0 >> nkvlog;
            const int key0 = row0 & mask;
#pragma unroll
            for (int ni = 0; ni < 4; ni++) {
                const int d = (int)(bn + wc + ni * 16 + li) - vtoff;
                short4v o = { f2bf(acc[mi][ni][0]), f2bf(acc[mi][ni][1]),
                              f2bf(acc[mi][ni][2]), f2bf(acc[mi][ni][3]) };
                *(short4v*)(VT + ((long)(bb * 512 + d) << nkvlog) + key0) = o;
            }
        }
    }
}

// Split-K=2 variant: blockIdx.z picks K-half; writes f32 partial z (M*N each).
// bias (if BIAS) applied in partial 0 only. Partials summed in ln_res.
template<int BIAS>
__global__ __launch_bounds__(256) void gemm_bt_sk(
    const short* __restrict__ A, const short* __restrict__ Bt,
    const float* __restrict__ bias, float* __restrict__ Cout,
    int M, int N, int K)
{
    __shared__ short Alds[2][128 * 32];
    __shared__ short Blds[2][128 * 32];
    const int tid  = threadIdx.x;
    const int wave = tid >> 6, lane = tid & 63;
    const int g = lane >> 4, li = lane & 15;
    const int z = blockIdx.z;
    const int Kh = K >> 1;

    const int gx = gridDim.x;
    int flat = blockIdx.y * gx + blockIdx.x;
    const int nwg = gx * gridDim.y;
    flat = (flat & 7) * (nwg >> 3) + (flat >> 3);
    const long bm = (long)(flat % gx) * 128;
    const long bn = (long)(flat / gx) * 128;

    const int wr = (wave >> 1) * 64;
    const int wc = (wave & 1) * 64;
    const int srow = wave * 32 + (lane >> 2);
    const int scol = (lane & 3) * 8;
    const short* Ap = A + (bm + srow) * (long)K + scol + (long)z * Kh;
    const short* Bp = Bt + (bn + srow) * (long)K + scol + (long)z * Kh;
    float* C = Cout + (long)z * M * N;

    auto STAGE = [&](int buf, int k0) {
        __builtin_amdgcn_global_load_lds(
            (const __attribute__((address_space(1))) void*)(Ap + k0),
            (__attribute__((address_space(3))) void*)(&Alds[buf][wave * 1024]), 16, 0, 0);
        __builtin_amdgcn_global_load_lds(
            (const __attribute__((address_space(1))) void*)(Ap + (long)16 * K + k0),
            (__attribute__((address_space(3))) void*)(&Alds[buf][wave * 1024 + 512]), 16, 0, 0);
        __builtin_amdgcn_global_load_lds(
            (const __attribute__((address_space(1))) void*)(Bp + k0),
            (__attribute__((address_space(3))) void*)(&Blds[buf][wave * 1024]), 16, 0, 0);
        __builtin_amdgcn_global_load_lds(
            (const __attribute__((address_space(1))) void*)(Bp + (long)16 * K + k0),
            (__attribute__((address_space(3))) void*)(&Blds[buf][wave * 1024 + 512]), 16, 0, 0);
    };

    floatx4 acc[4][4];
#pragma unroll
    for (int i = 0; i < 4; i++)
#pragma unroll
        for (int j = 0; j < 4; j++) acc[i][j] = (floatx4){0.f, 0.f, 0.f, 0.f};

    STAGE(0, 0);
    __syncthreads();
    int cur = 0;
    for (int k0 = 0; k0 < Kh; k0 += 32) {
        if (k0 + 32 < Kh) STAGE(cur ^ 1, k0 + 32);
        short8 af[4], bfr[4];
#pragma unroll
        for (int mi = 0; mi < 4; mi++)
            af[mi] = *(const short8*)(&Alds[cur][(wr + mi * 16 + li) * 32 + g * 8]);
#pragma unroll
        for (int ni = 0; ni < 4; ni++)
            bfr[ni] = *(const short8*)(&Blds[cur][(wc + ni * 16 + li) * 32 + g * 8]);
#pragma unroll
        for (int mi = 0; mi < 4; mi++)
#pragma unroll
            for (int ni = 0; ni < 4; ni++)
                acc[mi][ni] = __builtin_amdgcn_mfma_f32_16x16x32_bf16(
                    af[mi], bfr[ni], acc[mi][ni], 0, 0, 0);
        __syncthreads();
        cur ^= 1;
    }

#pragma unroll
    for (int mi = 0; mi < 4; mi++)
#pragma unroll
        for (int ni = 0; ni < 4; ni++) {
            const long col = bn + wc + ni * 16 + li;
            const float bv = (BIAS && z == 0) ? bias[col] : 0.f;
#pragma unroll
            for (int i = 0; i < 4; i++) {
                const long row = bm + wr + mi * 16 + g * 4 + i;
                C[row * N + col] = acc[mi][ni][i] + bv;
            }
        }
}

// ---------------------------------------------------------------- attention
// R9/R12 kernel + T5 s_setprio(1) around the two MFMA clusters (QK^T and PV).
// With 2 blocks/CU at different K-tile phases, the scheduler favors waves in
// their MFMA cluster over waves issuing staging/softmax (catalog: attn +4-7%).
// KT=32, 32 q/wave, T14 async staging, static-max softmax, LD=68/LDP=36,
// XCD-locality decode. Frozen structure otherwise.
__global__ __launch_bounds__(256) void attn_kernel(
    const short* __restrict__ Qg, const short* __restrict__ Kg,
    const short* __restrict__ VTg, short* __restrict__ Og,
    int NQ, int NK, int ldq, int ldk)
{
    constexpr int LD = 68, LDP = 36;
    __shared__ short Klds[32 * LD];       // [key][d]
    __shared__ short Vlds[64 * LD];       // [d][key]
    __shared__ short Plds[4][32 * LDP];   // per-wave [q][key], 32 q rows

    const int tid = threadIdx.x;
    const int wave = tid >> 6, lane = tid & 63;
    const int g = lane >> 4, li = lane & 15;

    const int nqb = NQ >> 7;
    const int i   = blockIdx.x;
    const int xcd = i & 7;
    const int t   = i >> 3;
    const int c   = t % nqb;
    const int gh  = t / nqb;
    const int grp = xcd + 8 * gh;         // 0..63
    const int b   = grp >> 3, h = grp & 7;
    const int q0  = c * 128 + wave * 32;

    const short* qptrA = Qg + ((long)(b * NQ + q0 + li) * ldq + h * 64);
    const short* qptrB = qptrA + (long)16 * ldq;
    short8 qfA[2], qfB[2];
#pragma unroll
    for (int f = 0; f < 2; f++) {
        short8 ta = *(const short8*)(qptrA + f * 32 + g * 8);
        short8 tb = *(const short8*)(qptrB + f * 32 + g * 8);
#pragma unroll
        for (int ii = 0; ii < 8; ii++) {
            ta[ii] = f2bf(bf2f(ta[ii]) * 0.18033688011112042f);
            tb[ii] = f2bf(bf2f(tb[ii]) * 0.18033688011112042f);
        }
        qfA[f] = ta; qfB[f] = tb;
    }

    floatx4 accA[4], accB[4];
#pragma unroll
    for (int s = 0; s < 4; s++) {
        accA[s] = (floatx4){0.f, 0.f, 0.f, 0.f};
        accB[s] = (floatx4){0.f, 0.f, 0.f, 0.f};
    }
    float lsumA = 0.f, lsumB = 0.f;

    const int skey = tid >> 3, sdc = (tid & 7) * 8;  // K staging: 32 keys x 64 d
    const int svd = tid >> 2, svk = (tid & 3) * 8;   // VT staging: 64 d x 32 keys
    const short* kp = Kg + (long)b * NK * ldk + h * 64 + (long)skey * ldk + sdc;
    const short* vp = VTg + ((long)(b * 512 + h * 64 + svd)) * NK + svk;

    short8 kreg = *(const short8*)kp;  kp += (long)32 * ldk;
    short8 vreg = *(const short8*)vp;  vp += 32;

    for (int kt = 0; kt < NK; kt += 32) {
        __syncthreads();
        *(short8*)(Klds + skey * LD + sdc) = kreg;
        *(short8*)(Vlds + svd * LD + svk) = vreg;
        __syncthreads();
        if (kt + 32 < NK) {
            kreg = *(const short8*)kp;  kp += (long)32 * ldk;
            vreg = *(const short8*)vp;  vp += 32;
        }

        // S^T subtiles: lane holds S[key = sub*16 + 4g + i][q = li (A) / 16+li (B)]
        floatx4 sA0 = (floatx4){0.f, 0.f, 0.f, 0.f};
        floatx4 sA1 = (floatx4){0.f, 0.f, 0.f, 0.f};
        floatx4 sB0 = (floatx4){0.f, 0.f, 0.f, 0.f};
        floatx4 sB1 = (floatx4){0.f, 0.f, 0.f, 0.f};
        {
            short8 k00 = *(const short8*)(Klds + li * LD + g * 8);
            short8 k01 = *(const short8*)(Klds + li * LD + 32 + g * 8);
            short8 k10 = *(const short8*)(Klds + (16 + li) * LD + g * 8);
            short8 k11 = *(const short8*)(Klds + (16 + li) * LD + 32 + g * 8);
            __builtin_amdgcn_s_setprio(1);
            sA0 = __builtin_amdgcn_mfma_f32_16x16x32_bf16(k00, qfA[0], sA0, 0, 0, 0);
            sA0 = __builtin_amdgcn_mfma_f32_16x16x32_bf16(k01, qfA[1], sA0, 0, 0, 0);
            sA1 = __builtin_amdgcn_mfma_f32_16x16x32_bf16(k10, qfA[0], sA1, 0, 0, 0);
            sA1 = __builtin_amdgcn_mfma_f32_16x16x32_bf16(k11, qfA[1], sA1, 0, 0, 0);
            sB0 = __builtin_amdgcn_mfma_f32_16x16x32_bf16(k00, qfB[0], sB0, 0, 0, 0);
            sB0 = __builtin_amdgcn_mfma_f32_16x16x32_bf16(k01, qfB[1], sB0, 0, 0, 0);
            sB1 = __builtin_amdgcn_mfma_f32_16x16x32_bf16(k10, qfB[0], sB1, 0, 0, 0);
            sB1 = __builtin_amdgcn_mfma_f32_16x16x32_bf16(k11, qfB[1], sB1, 0, 0, 0);
            __builtin_amdgcn_s_setprio(0);
        }

        // static-max softmax: p = exp2(S)
        const float a0 = exp2f(sA0[0]), a1 = exp2f(sA0[1]);
        const float a2 = exp2f(sA0[2]), a3 = exp2f(sA0[3]);
        const float a4 = exp2f(sA1[0]), a5 = exp2f(sA1[1]);
        const float a6 = exp2f(sA1[2]), a7 = exp2f(sA1[3]);
        lsumA += ((a0 + a1) + (a2 + a3)) + ((a4 + a5) + (a6 + a7));
        const float b0 = exp2f(sB0[0]), b1 = exp2f(sB0[1]);
        const float b2 = exp2f(sB0[2]), b3 = exp2f(sB0[3]);
        const float b4 = exp2f(sB1[0]), b5 = exp2f(sB1[1]);
        const float b6 = exp2f(sB1[2]), b7 = exp2f(sB1[3]);
        lsumB += ((b0 + b1) + (b2 + b3)) + ((b4 + b5) + (b6 + b7));

        short4v pa0 = { f2bf_tr(a0), f2bf_tr(a1), f2bf_tr(a2), f2bf_tr(a3) };
        short4v pa1 = { f2bf_tr(a4), f2bf_tr(a5), f2bf_tr(a6), f2bf_tr(a7) };
        short4v pb0 = { f2bf_tr(b0), f2bf_tr(b1), f2bf_tr(b2), f2bf_tr(b3) };
        short4v pb1 = { f2bf_tr(b4), f2bf_tr(b5), f2bf_tr(b6), f2bf_tr(b7) };
        *(short4v*)(Plds[wave] + li * LDP + g * 4) = pa0;
        *(short4v*)(Plds[wave] + li * LDP + 16 + g * 4) = pa1;
        *(short4v*)(Plds[wave] + (16 + li) * LDP + g * 4) = pb0;
        *(short4v*)(Plds[wave] + (16 + li) * LDP + 16 + g * 4) = pb1;
        short8 pfA = *(const short8*)(Plds[wave] + li * LDP + g * 8);
        short8 pfB = *(const short8*)(Plds[wave] + (16 + li) * LDP + g * 8);

        // O^T slices: acc[s] += VT_slice(16d x 32k) . P^T(32k x 16q)
        __builtin_amdgcn_s_setprio(1);
#pragma unroll
        for (int s = 0; s < 4; s++) {
            short8 vf = *(const short8*)(Vlds + (s * 16 + li) * LD + g * 8);
            accA[s] = __builtin_amdgcn_mfma_f32_16x16x32_bf16(vf, pfA, accA[s], 0, 0, 0);
            accB[s] = __builtin_amdgcn_mfma_f32_16x16x32_bf16(vf, pfB, accB[s], 0, 0, 0);
        }
        __builtin_amdgcn_s_setprio(0);
    }

    lsumA += __shfl_xor(lsumA, 16);
    lsumA += __shfl_xor(lsumA, 32);
    lsumB += __shfl_xor(lsumB, 16);
    lsumB += __shfl_xor(lsumB, 32);
    const float invA = 1.f / lsumA;
    const float invB = 1.f / lsumB;
    short* optrA = Og + ((long)(b * NQ + q0 + li) * 512 + h * 64);
    short* optrB = optrA + (long)16 * 512;
#pragma unroll
    for (int s = 0; s < 4; s++) {
        short4v oa = { f2bf(accA[s][0] * invA), f2bf(accA[s][1] * invA),
                       f2bf(accA[s][2] * invA), f2bf(accA[s][3] * invA) };
        short4v ob = { f2bf(accB[s][0] * invB), f2bf(accB[s][1] * invB),
                       f2bf(accB[s][2] * invB), f2bf(accB[s][3] * invB) };
        *(short4v*)(optrA + s * 16 + g * 4) = oa;
        *(short4v*)(optrB + s * 16 + g * 4) = ob;
    }
}

// ---------------------------------------------------------------- small kernels
__global__ __launch_bounds__(256) void add_conv2(
    const float* __restrict__ a, const float* __restrict__ b,
    float* __restrict__ of, short* __restrict__ ob1, short* __restrict__ ob2)
{
    const long i = (long)(blockIdx.x * 256 + threadIdx.x) * 4;
    const float4 va = *(const float4*)(a + i);
    float4 vs = va;
    if (b) {
        const float4 vb = *(const float4*)(b + i);
        vs.x += vb.x; vs.y += vb.y; vs.z += vb.z; vs.w += vb.w;
    }
    if (of) *(float4*)(of + i) = vs;
    short4v o1 = { f2bf(vs.x), f2bf(vs.y), f2bf(vs.z), f2bf(vs.w) };
    *(short4v*)(ob1 + i) = o1;
    if (ob2) {
        short4v o2 = { f2bf(va.x), f2bf(va.y), f2bf(va.z), f2bf(va.w) };
        *(short4v*)(ob2 + i) = o2;
    }
}

// y = LayerNorm(X [+X2])*g + b + res [+ postadd]; outF f32, outB bf16 (opt)
__global__ __launch_bounds__(256) void ln_res_kernel(
    const float* __restrict__ X, const float* __restrict__ X2,
    const float* __restrict__ gam, const float* __restrict__ bet,
    const float* __restrict__ res, const float* __restrict__ postadd,
    float* __restrict__ outF, short* __restrict__ outB)
{
    const int row = blockIdx.x * 4 + (threadIdx.x >> 6);
    const int lane = threadIdx.x & 63;
    const long base = (long)row * 512 + lane * 8;
    float x[8];
    *(float4*)(x) = *(const float4*)(X + base);
    *(float4*)(x + 4) = *(const float4*)(X + base + 4);
    if (X2) {
        float x2[8];
        *(float4*)(x2) = *(const float4*)(X2 + base);
        *(float4*)(x2 + 4) = *(const float4*)(X2 + base + 4);
#pragma unroll
        for (int i = 0; i < 8; i++) x[i] += x2[i];
    }
    float s = x[0] + x[1] + x[2] + x[3] + x[4] + x[5] + x[6] + x[7];
#pragma unroll
    for (int o = 1; o < 64; o <<= 1) s += __shfl_xor(s, o);
    const float mu = s * (1.0f / 512.0f);
    float vs = 0.f;
#pragma unroll
    for (int i = 0; i < 8; i++) { const float d = x[i] - mu; vs += d * d; }
#pragma unroll
    for (int o = 1; o < 64; o <<= 1) vs += __shfl_xor(vs, o);
    const float rs = rsqrtf(vs * (1.0f / 512.0f) + 1e-5f);

    float gv[8], bv[8], rv[8];
    *(float4*)(gv) = *(const float4*)(gam + lane * 8);
    *(float4*)(gv + 4) = *(const float4*)(gam + lane * 8 + 4);
    *(float4*)(bv) = *(const float4*)(bet + lane * 8);
    *(float4*)(bv + 4) = *(const float4*)(bet + lane * 8 + 4);
    *(float4*)(rv) = *(const float4*)(res + base);
    *(float4*)(rv + 4) = *(const float4*)(res + base + 4);

    float y[8];
#pragma unroll
    for (int i = 0; i < 8; i++) y[i] = (x[i] - mu) * rs * gv[i] + bv[i] + rv[i];
    if (postadd) {
        float pv[8];
        *(float4*)(pv) = *(const float4*)(postadd + base);
        *(float4*)(pv + 4) = *(const float4*)(postadd + base + 4);
#pragma unroll
        for (int i = 0; i < 8; i++) y[i] += pv[i];
    }
    *(float4*)(outF + base) = *(float4*)(y);
    *(float4*)(outF + base + 4) = *(float4*)(y + 4);
    if (outB) {
        short8 ob;
#pragma unroll
        for (int i = 0; i < 8; i++) ob[i] = f2bf(y[i]);
        *(short8*)(outB + base) = ob;
    }
}

// batched W (K,N) f32 -> Wt (N,K) bf16; blockIdx.z selects source/dest
__global__ __launch_bounds__(256) void wtrans8(
    const float* __restrict__ w0, const float* __restrict__ w1,
    const float* __restrict__ w2, const float* __restrict__ w3,
    const float* __restrict__ w4, const float* __restrict__ w5,
    const float* __restrict__ w6, const float* __restrict__ w7,
    short* __restrict__ o0, short* __restrict__ o1,
    short* __restrict__ o2, short* __restrict__ o3,
    short* __restrict__ o4, short* __restrict__ o5,
    short* __restrict__ o6, short* __restrict__ o7,
    int K, int N)
{
    const float* Ws[8] = {w0, w1, w2, w3, w4, w5, w6, w7};
    short* Os[8] = {o0, o1, o2, o3, o4, o5, o6, o7};
    const float* W = Ws[blockIdx.z];
    short* Wt = Os[blockIdx.z];
    __shared__ short t[32][33];
    const int n0 = blockIdx.x * 32, k0 = blockIdx.y * 32;
    const int tx = threadIdx.x & 31, ty = threadIdx.x >> 5;
    for (int r = ty; r < 32; r += 8)
        t[r][tx] = f2bf(W[(long)(k0 + r) * N + n0 + tx]);
    __syncthreads();
    for (int r = ty; r < 32; r += 8)
        Wt[(long)(n0 + r) * K + k0 + tx] = t[tx][r];
}

// ---------------------------------------------------------------- launch
extern "C" void kernel_launch(void* const* d_in, const int* in_sizes, int n_in,
                              void* d_out, int out_size, void* d_ws, size_t ws_size,
                              hipStream_t stream)
{
    (void)in_sizes; (void)n_in; (void)out_size; (void)ws_size;
    const float* tgt   = (const float*)d_in[0];
    const float* mem   = (const float*)d_in[1];
    const float* pos   = (const float*)d_in[2];
    const float* qpos  = (const float*)d_in[3];
    const float* a0_wq = (const float*)d_in[4];
    const float* a0_wk = (const float*)d_in[5];
    const float* a0_wv = (const float*)d_in[6];
    const float* a0_wo = (const float*)d_in[7];
    const float* a0_bo = (const float*)d_in[8];
    const float* a0_g  = (const float*)d_in[9];
    const float* a0_b  = (const float*)d_in[10];
    const float* f0_w1 = (const float*)d_in[11];
    const float* f0_b1 = (const float*)d_in[12];
    const float* f0_w2 = (const float*)d_in[13];
    const float* f0_b2 = (const float*)d_in[14];
    const float* f0_g  = (const float*)d_in[15];
    const float* f0_b  = (const float*)d_in[16];
    const float* a1_wq = (const float*)d_in[17];
    const float* a1_wk = (const float*)d_in[18];
    const float* a1_wv = (const float*)d_in[19];
    const float* a1_wo = (const float*)d_in[20];
    const float* a1_bo = (const float*)d_in[21];
    const float* a1_g  = (const float*)d_in[22];
    const float* a1_b  = (const float*)d_in[23];
    const float* f1_w1 = (const float*)d_in[24];
    const float* f1_b1 = (const float*)d_in[25];
    const float* f1_w2 = (const float*)d_in[26];
    const float* f1_b2 = (const float*)d_in[27];
    const float* f1_g  = (const float*)d_in[28];
    const float* f1_b  = (const float*)d_in[29];

    const int M1 = 8 * 1024;   // 8192 query rows
    const int M2 = 8 * 2048;   // 16384 memory rows
    const size_t MB = 1ull << 20;
    char* ws = (char*)d_ws;

    float* resid = (float*)(ws + 0 * MB);       // 16MB
    float* xf    = (float*)(ws + 16 * MB);      // 16MB
    short* xb    = (short*)(ws + 32 * MB);      // 8MB
    short* wb    = (short*)(ws + 40 * MB);      // 12MB bf16 W^T bank
    short* a0_wqt = wb;            short* a0_wkt = wb + 262144;   // Wq^T||Wk^T||Wv^T
    short* a0_wvt = wb + 524288;   short* a0_wot = wb + 786432;
    short* f0_w1t = wb + 1048576;  short* f0_w2t = wb + 2097152;
    short* a1_wqt = wb + 3145728;  short* a1_wkt = wb + 3407872;   // Wk^T||Wv^T
    short* a1_wvt = wb + 3670016;  short* a1_wot = wb + 3932160;
    short* f1_w1t = wb + 4194304;  short* f1_w2t = wb + 5242880;
    char* S = ws + 56 * MB;                      // stage scratch (max used: +88MB)

    wtrans8<<<dim3(16, 16, 8), 256, 0, stream>>>(
        a0_wq, a0_wk, a0_wv, a0_wo, a1_wq, a1_wk, a1_wv, a1_wo,
        a0_wqt, a0_wkt, a0_wvt, a0_wot, a1_wqt, a1_wkt, a1_wvt, a1_wot, 512, 512);
    wtrans8<<<dim3(64, 16, 2), 256, 0, stream>>>(
        f0_w1, f1_w1, nullptr, nullptr, nullptr, nullptr, nullptr, nullptr,
        f0_w1t, f1_w1t, nullptr, nullptr, nullptr, nullptr, nullptr, nullptr, 512, 2048);
    wtrans8<<<dim3(16, 64, 2), 256, 0, stream>>>(
        f0_w2, f1_w2, nullptr, nullptr, nullptr, nullptr, nullptr, nullptr,
        f0_w2t, f1_w2t, nullptr, nullptr, nullptr, nullptr, nullptr, nullptr, 2048, 512);

    // ---------------- block A0: self-attention ----------------
    short* QKs  = (short*)(S + 0 * MB);    // 16MB: [8192][1024] = Q||K (ld 1024)
    short* VsT  = (short*)(S + 16 * MB);   // 8MB:  [8][512][1024] V^T
    short* AOs  = (short*)(S + 24 * MB);   // 8MB
    float* P0a  = (float*)(S + 32 * MB);   // 16MB
    float* P1a  = (float*)(S + 48 * MB);   // 16MB
    short* q0b  = (short*)(S + 64 * MB);   // 8MB
    short* tgtb = (short*)(S + 72 * MB);   // 8MB

    add_conv2<<<4096, 256, 0, stream>>>(tgt, qpos, resid, q0b, tgtb);

    // fused QKV projection; V section written directly transposed to VsT
    gemm_bt2vt<<<dim3(64, 12), 256, 0, stream>>>(q0b, tgtb, a0_wqt, QKs, VsT,
                                                 M1, 1536, 512, 1024, 1024, 1024, 10);
    attn_kernel<<<512, 256, 0, stream>>>(QKs, QKs + 512, VsT, AOs,
                                         1024, 1024, 1024, 1024);
    gemm_bt_sk<1><<<dim3(64, 4, 2), 256, 0, stream>>>(AOs, a0_wot, a0_bo, P0a,
                                                      M1, 512, 512);
    ln_res_kernel<<<2048, 256, 0, stream>>>(P0a, P1a, a0_g, a0_b, resid, nullptr, xf, xb);

    // ---------------- block F0: FFN ----------------
    short* Hb  = (short*)(S + 0 * MB);     // 32MB (QKs/VsT/AOs dead)
    float* P0f = (float*)(S + 32 * MB);    // 16MB (over dead P0a)
    float* P1f = (float*)(S + 48 * MB);    // 16MB (over dead P1a)
    short* qcb = (short*)(S + 80 * MB);    // 8MB (A1 q input, written by ln)
    gemm_bt<1,1,1><<<dim3(64, 16), 256, 0, stream>>>(xb, f0_w1t, f0_b1, Hb, M1, 2048, 512);
    gemm_bt_sk<1><<<dim3(64, 4, 2), 256, 0, stream>>>(Hb, f0_w2t, f0_b2, P0f,
                                                      M1, 512, 2048);
    // y = LN(P0+P1)+xf ; resid = y+qpos (f32), qcb = bf16(y+qpos)
    ln_res_kernel<<<2048, 256, 0, stream>>>(P0f, P1f, f0_g, f0_b, xf, qpos, resid, qcb);

    // ---------------- block A1: cross-attention ----------------
    // Lifetimes: Hb dead after FFN2-sk; P0f/P1f dead after F0-ln; q0b/tgtb dead.
    // Kc/VcT dead after attn -> P0c/P1c overwrite them.
    short* kcb  = (short*)(S + 0 * MB);    // 16MB (over dead Hb)
    short* memb = (short*)(S + 16 * MB);   // 16MB
    short* Kc   = (short*)(S + 32 * MB);   // 16MB: [16384][512] dense K
    short* VcT  = (short*)(S + 48 * MB);   // 16MB: [8][512][2048] V^T
    short* Qc   = (short*)(S + 64 * MB);   // 8MB
    short* AOc  = (short*)(S + 72 * MB);   // 8MB
    float* P0c  = (float*)(S + 32 * MB);   // 16MB (over dead Kc, after attn)
    float* P1c  = (float*)(S + 48 * MB);   // 16MB (over dead VcT)

    add_conv2<<<8192, 256, 0, stream>>>(mem, pos, nullptr, kcb, memb);

    gemm_bt<0,0,1><<<dim3(64, 4), 256, 0, stream>>>(qcb, a1_wqt, nullptr, Qc, M1, 512, 512);
    // fused KV projection; K -> Kc (dense ld 512), V -> VcT transposed
    gemm_bt2vt<<<dim3(128, 8), 256, 0, stream>>>(kcb, memb, a1_wkt, Kc, VcT,
                                                 M2, 1024, 512, 512, 512, 512, 11);
    attn_kernel<<<512, 256, 0, stream>>>(Qc, Kc, VcT, AOc,
                                         1024, 2048, 512, 512);
    gemm_bt_sk<1><<<dim3(64, 4, 2), 256, 0, stream>>>(AOc, a1_wot, a1_bo, P0c,
                                                      M1, 512, 512);
    ln_res_kernel<<<2048, 256, 0, stream>>>(P0c, P1c, a1_g, a1_b, resid, nullptr, xf, xb);

    // ---------------- block F1: FFN (writes d_out) ----------------
    short* Hb2  = (short*)(S + 0 * MB);    // 32MB (kcb/memb dead)
    float* P0g  = (float*)(S + 32 * MB);   // 16MB (P0c dead after A1-ln)
    float* P1g  = (float*)(S + 48 * MB);   // 16MB
    gemm_bt<1,1,1><<<dim3(64, 16), 256, 0, stream>>>(xb, f1_w1t, f1_b1, Hb2, M1, 2048, 512);
    gemm_bt_sk<1><<<dim3(64, 4, 2), 256, 0, stream>>>(Hb2, f1_w2t, f1_b2, P0g,
                                                      M1, 512, 2048);
    ln_res_kernel<<<2048, 256, 0, stream>>>(P0g, P1g, f1_g, f1_b, xf, nullptr,
                                            (float*)d_out, nullptr);
}